// Round 17
// baseline (894.673 us; speedup 1.0000x reference)
//
#include <hip/hip_runtime.h>
#include <cstddef>

// ---------------------------------------------------------------------------
// FPNIoUNetHR forward — round 17: conv LDS shrunk to 32 KB (5 blocks/CU, was
// 4 at 36 KB). Epilogue split into two 64-row passes. Otherwise = r16
// (single-barrier K-step, A in regs via asm, 4 B-buffers).
// S=64, C=256, H=W=36, N=16.
// ---------------------------------------------------------------------------

typedef _Float16 f16;
typedef __attribute__((ext_vector_type(8))) _Float16 f16x8;
typedef __attribute__((ext_vector_type(4))) float f32x4;

__device__ __forceinline__ void gload16(const void* g, void* l) {
  __builtin_amdgcn_global_load_lds((const __attribute__((address_space(1))) void*)g,
                                   (__attribute__((address_space(3))) void*)l, 16, 0, 0);
}

// async global->VGPR load invisible to the compiler's waitcnt pass.
__device__ __forceinline__ f16x8 gload_reg(const f16* p) {
  f16x8 v;
  asm volatile("global_load_dwordx4 %0, %1, off" : "=&v"(v) : "v"(p) : "memory");
  return v;
}

#define WAITB(N) asm volatile("s_waitcnt vmcnt(" #N ")\n\ts_barrier" ::: "memory")
#define LGKB()   asm volatile("s_waitcnt lgkmcnt(0)\n\ts_barrier" ::: "memory")

static __device__ __forceinline__ float hat_int(float x) {
  float u = fminf(1.f, fmaxf(-1.f, x));
  float a = 0.5f * (1.f + u) * (1.f + u);
  float b = 0.5f + u - 0.5f * u * u;
  return (u <= 0.f) ? a : b;
}

// Packed GEMM operand layout: element (row,k) of a row-major [M][K] matrix ->
// [row/128][k/32][(k/8)%4][row%128][k%8]. One k-step chunk (128 rows x 32 k)
// is 8 KB contiguous, exactly the LDS image the MFMA frag reads want.
static __device__ __forceinline__ size_t pk_off(int row, int k, int K) {
  return (size_t)(row >> 7) * ((size_t)K * 128) + (size_t)(k >> 5) * 4096
       + (size_t)((((k >> 3) & 3) * 128 + (row & 127)) * 8 + (k & 7));
}

// ---- coalesced pad: fp32 CHW input -> FT2 f16, LDS transpose --------------
__global__ __launch_bounds__(256) void k_padT(const float* __restrict__ src,
                                              f16* __restrict__ FT) {
  __shared__ f16 sT[8][1300];
  const int img = blockIdx.x, kk = blockIdx.y;
  const float* sp = src + ((size_t)img * 256 + kk * 8) * 1296;
#pragma unroll
  for (int c = 0; c < 8; ++c)
    for (int i = threadIdx.x; i < 1296; i += 256)
      sT[c][i] = (f16)sp[c * 1296 + i];
  __syncthreads();
  f16* op = FT + ((size_t)img * 32 + kk) * 1444 * 8;
  for (int i = threadIdx.x; i < 148; i += 256) {
    int r, cc;
    if (i < 38)       { r = 0;          cc = i; }
    else if (i < 76)  { r = 37;         cc = i - 38; }
    else if (i < 112) { r = i - 76 + 1; cc = 0; }
    else              { r = i - 112 + 1; cc = 37; }
    f16x8 z = {};
    *reinterpret_cast<f16x8*>(op + (r * 38 + cc) * 8) = z;
  }
  for (int i = threadIdx.x; i < 1296; i += 256) {
    const int h = i / 36, w = i - h * 36;
    f16x8 v;
#pragma unroll
    for (int c = 0; c < 8; ++c) v[c] = sT[c][i];
    *reinterpret_cast<f16x8*>(op + ((h + 1) * 38 + w + 1) * 8) = v;
  }
}

// ---- pad HWC f16 conv output + BN+ReLU -> FT2 f16 -------------------------
__global__ void k_pad2(const f16* __restrict__ yH, f16* __restrict__ FT,
                       const float* __restrict__ mean, const float* __restrict__ istd,
                       const float* __restrict__ g, const float* __restrict__ be) {
  const int img = blockIdx.x, h = blockIdx.y, c = threadIdx.x;
  const float sc = istd[c] * g[c];
  const float sh = be[c] - mean[c] * sc;
  const f16* sp = yH + ((size_t)img * 1296 + h * 36) * 256 + c;
  f16* op = FT + (((size_t)img * 32 + (c >> 3)) * 1444 + (h + 1) * 38 + 1) * 8 + (c & 7);
#pragma unroll 4
  for (int w = 0; w < 36; ++w) {
    float v = fmaxf(fmaf((float)sp[w * 256], sc, sh), 0.f);
    op[w * 8] = (f16)v;
  }
}

// ---- conv weights [256][256][3][3] fp32 -> packed f16 ---------------------
__global__ void k_pack_wc(const float* __restrict__ w, f16* __restrict__ dst) {
  int i = blockIdx.x * 256 + threadIdx.x;   // < 589,824
  int oct = i / 294912;
  int r = i - oct * 294912;
  int ks = r >> 12;
  int r2 = r & 4095;
  int koct = r2 >> 10;
  int r3 = r2 & 1023;
  int row = r3 >> 3, kj = r3 & 7;
  int k = ks * 32 + koct * 8 + kj;
  int t = k >> 8, c = k & 255;
  int oc = oct * 128 + row;
  dst[i] = (f16)w[(oc * 256 + c) * 9 + t];
}

// ---- tiled LDS transpose: row-major [M][K] -> pk layout (zero-fill) -------
__global__ __launch_bounds__(256) void k_packx_h(
    const f16* __restrict__ src, f16* __restrict__ dst, int M, int K) {
  __shared__ f16 sT[128][264];
  const int k0 = blockIdx.x * 256, r0 = blockIdx.y * 128;
  const int t = threadIdx.x;
  const int rl = t >> 5, kk = (t & 31) * 8;
  for (int rnd = 0; rnd < 16; ++rnd) {
    const int row_l = rl + rnd * 8;
    const int row = r0 + row_l;
    if (row < M) {
      f16x8 v = *reinterpret_cast<const f16x8*>(src + (size_t)row * K + k0 + kk);
      *reinterpret_cast<f16x8*>(&sT[row_l][kk]) = v;
    }
  }
  __syncthreads();
  const size_t base = (size_t)(r0 >> 7) * ((size_t)K * 128) + (size_t)(k0 >> 5) * 4096;
#pragma unroll
  for (int cs = 0; cs < 8; ++cs) {
#pragma unroll
    for (int half = 0; half < 2; ++half) {
      const int e = half * 256 + t;
      const int koct = e >> 7, row_l = e & 127;
      f16x8 v = {};
      if (r0 + row_l < M)
        v = *reinterpret_cast<const f16x8*>(&sT[row_l][cs * 32 + koct * 8]);
      *reinterpret_cast<f16x8*>(dst + base + (size_t)cs * 4096 + e * 8) = v;
    }
  }
}

__global__ __launch_bounds__(256) void k_packx_f(
    const float* __restrict__ src, f16* __restrict__ dst, int M, int K) {
  __shared__ f16 sT[128][264];
  const int k0 = blockIdx.x * 256, r0 = blockIdx.y * 128;
  const int t = threadIdx.x;
  const int rl = t >> 5, kk = (t & 31) * 8;
  for (int rnd = 0; rnd < 16; ++rnd) {
    const int row_l = rl + rnd * 8;
    const int row = r0 + row_l;
    if (row < M) {
      const float4* sp = reinterpret_cast<const float4*>(src + (size_t)row * K + k0 + kk);
      float4 a = sp[0], b = sp[1];
      f16* o = &sT[row_l][kk];
      o[0] = (f16)a.x; o[1] = (f16)a.y; o[2] = (f16)a.z; o[3] = (f16)a.w;
      o[4] = (f16)b.x; o[5] = (f16)b.y; o[6] = (f16)b.z; o[7] = (f16)b.w;
    }
  }
  __syncthreads();
  const size_t base = (size_t)(r0 >> 7) * ((size_t)K * 128) + (size_t)(k0 >> 5) * 4096;
#pragma unroll
  for (int cs = 0; cs < 8; ++cs) {
#pragma unroll
    for (int half = 0; half < 2; ++half) {
      const int e = half * 256 + t;
      const int koct = e >> 7, row_l = e & 127;
      f16x8 v = {};
      if (r0 + row_l < M)
        v = *reinterpret_cast<const f16x8*>(&sT[row_l][cs * 32 + koct * 8]);
      *reinterpret_cast<f16x8*>(dst + base + (size_t)cs * 4096 + e * 8) = v;
    }
  }
}

// ---- 3x3 conv: A in regs (asm), B via 4 LDS bufs, ONE barrier per step ----
// LDS exactly 32 KB (4x8KB B bufs); epilogue = two 64-row passes in 17.4 KB.
__global__ __launch_bounds__(256, 2) void k_conv_mfma(
    const f16* __restrict__ Wpk, const f16* __restrict__ FT2,
    const float* __restrict__ bias, f16* __restrict__ yH,
    float* __restrict__ psc) {
  __shared__ __align__(16) char smem[32768];   // 4x8KB B; epilogue 64x136 f16
  f16x8* sB = (f16x8*)smem;            // 4 buffers x 512
  const int bid = blockIdx.x;
  const int orig = (bid & 7) * 176 + (bid >> 3);   // bijective: 1408 % 8 == 0
  const int img = orig / 22;
  const int rem = orig - img * 22;
  const int oct = rem / 11;
  const int pt  = rem - oct * 11;
  const int m0 = oct * 128;
  const int p0 = pt * 128;
  const int tid = threadIdx.x;
  const int lane = tid & 63;
  const int wv = tid >> 6;
  const int wr = wv >> 1, wc = wv & 1;

  const f16* aFrag = Wpk + (size_t)oct * 294912 + ((lane >> 4) << 10)
                   + ((size_t)(wr * 64 + (lane & 15)) << 3);
  const f16* ftImg = FT2 + (size_t)img * 32 * 1444 * 8;
  int pos0 = p0 + lane;
  int pc0 = min(pos0, 1295);
  int pc1 = min(pos0 + 64, 1295);
  int pb0 = (pc0 / 36) * 38 + (pc0 % 36);
  int pb1 = (pc1 / 36) * 38 + (pc1 % 36);

  const int loff = wv * 2048 + lane * 16;

  auto stageB = [&](int buf, int ks) {
    const int t = ks >> 3;
    const int dy = t / 3, dx = t - dy * 3;
    const int cs = ks & 7;
    const int dyx = dy * 38 + dx;
    char* lB = (char*)sB + buf * 8192 + loff;
    const f16* bp = ftImg + ((size_t)(cs * 4 + wv) * 1444 + dyx) * 8;
    gload16(bp + pb0 * 8, lB);
    gload16(bp + pb1 * 8, lB + 1024);
  };

#define LOADA(ASET, KS)                                                        \
  {                                                                            \
    const f16* _p = aFrag + (size_t)(KS) * 4096;                               \
    ASET[0] = gload_reg(_p);                                                   \
    ASET[1] = gload_reg(_p + 128);                                             \
    ASET[2] = gload_reg(_p + 256);                                             \
    ASET[3] = gload_reg(_p + 384);                                             \
  }

  f32x4 acc[4][4] = {};
  const int fidxB = ((lane >> 4) << 7) + wc * 64 + (lane & 15);
  f16x8 A0[4], A1[4], A2[4];

  stageB(0, 0); LOADA(A0, 0);
  stageB(1, 1); LOADA(A1, 1);
  stageB(2, 2); LOADA(A2, 2);   // 18 VMEM ops in flight per wave

#define CSTEP(ASET, BUF, RBUF, KS)                                             \
  {                                                                            \
    const int rr = 71 - (KS);                                                  \
    if (rr >= 2)      WAITB(12);                                               \
    else if (rr == 1) WAITB(6);                                                \
    else              WAITB(0);                                                \
    __builtin_amdgcn_sched_barrier(0);                                         \
    f16x8 bf[4];                                                               \
    _Pragma("unroll") for (int j = 0; j < 4; ++j)                              \
      bf[j] = sB[(BUF) * 512 + fidxB + j * 16];                                \
    __builtin_amdgcn_s_setprio(1);                                             \
    _Pragma("unroll") for (int ii = 0; ii < 4; ++ii)                           \
      _Pragma("unroll") for (int jj = 0; jj < 4; ++jj)                         \
        acc[ii][jj] = __builtin_amdgcn_mfma_f32_16x16x32_f16(ASET[ii], bf[jj], acc[ii][jj], 0, 0, 0); \
    __builtin_amdgcn_s_setprio(0);                                             \
    if ((KS) + 3 < 72) { stageB(RBUF, (KS) + 3); LOADA(ASET, (KS) + 3); }      \
  }

  for (int ks = 0; ks < 72; ks += 12) {
    CSTEP(A0, 0, 3, ks);
    CSTEP(A1, 1, 0, ks + 1);
    CSTEP(A2, 2, 1, ks + 2);
    CSTEP(A0, 3, 2, ks + 3);
    CSTEP(A1, 0, 3, ks + 4);
    CSTEP(A2, 1, 0, ks + 5);
    CSTEP(A0, 2, 1, ks + 6);
    CSTEP(A1, 3, 2, ks + 7);
    CSTEP(A2, 0, 3, ks + 8);
    CSTEP(A0, 1, 0, ks + 9);
    CSTEP(A1, 2, 1, ks + 10);
    CSTEP(A2, 3, 2, ks + 11);
  }
#undef CSTEP
#undef LOADA

  // ---- epilogue: two 64-row passes through a 64x136 LDS tile --------------
  __syncthreads();
  f16* sE = (f16*)smem;                 // 64 x 136 f16 = 17.4 KB
  const int ocl = wr * 64 + ((lane >> 4) << 2);
  const int nvalid = min(128, 1296 - p0);
  const int half = tid >> 7, cc = tid & 127;
  float sacc = 0.f, ssacc = 0.f;
  f16* yb = yH + (size_t)img * 1296 * 256 + m0;
#pragma unroll
  for (int pass = 0; pass < 2; ++pass) {
    if (wc == pass) {   // this wave's fragments live in rows pass*64..+63
#pragma unroll
      for (int i = 0; i < 4; ++i) {
        const int oc0 = m0 + ocl + i * 16;
        float b0 = bias[oc0], b1 = bias[oc0 + 1], b2 = bias[oc0 + 2], b3 = bias[oc0 + 3];
#pragma unroll
        for (int j = 0; j < 4; ++j) {
          f16* e = &sE[(j * 16 + (lane & 15)) * 136 + ocl + i * 16];
          e[0] = (f16)(acc[i][j][0] + b0);
          e[1] = (f16)(acc[i][j][1] + b1);
          e[2] = (f16)(acc[i][j][2] + b2);
          e[3] = (f16)(acc[i][j][3] + b3);
        }
      }
    }
    __syncthreads();
    // coalesced stores of this pass's 64 rows
#pragma unroll
    for (int it = 0; it < 4; ++it) {
      const int e = (it * 256 + tid) * 8;   // 8192 f16 per pass
      const int row = e >> 7;               // 0..63
      const int oc = e & 127;
      const int col = p0 + pass * 64 + row;
      if (col < 1296)
        *reinterpret_cast<f16x8*>(yb + (size_t)col * 256 + oc) =
          *reinterpret_cast<const f16x8*>(&sE[row * 136 + oc]);
    }
    // stats for this pass (thread covers 32 rows of the 64)
    const int vlim = min(64, nvalid - pass * 64);
    const int lr0 = half * 32;
    const int lr1 = min(vlim, lr0 + 32);
    for (int lr = lr0; lr < lr1; ++lr) {
      float v = (float)sE[lr * 136 + cc];
      sacc += v; ssacc += v * v;
    }
    __syncthreads();   // sE reads done before next pass overwrites
  }
  const int bi = (half * 704 + img * 11 + pt) * 256 + m0 + cc;
  psc[bi] = sacc;
  psc[360448 + bi] = ssacc;
}

// ---- fold conv stats partials: 1408 entries -> 8 -> mean/istd -------------
__global__ void k_chan_fold8(const float* __restrict__ psc, float* __restrict__ out2) {
  const int z = blockIdx.x, c = threadIdx.x;
  float s = 0.f, ss = 0.f;
  for (int i = z * 176; i < z * 176 + 176; ++i) {
    s += psc[i * 256 + c];
    ss += psc[360448 + i * 256 + c];
  }
  out2[z * 256 + c] = s;
  out2[2048 + z * 256 + c] = ss;
}

__global__ void k_chan_final2(const float* __restrict__ out2,
                              float* __restrict__ mean, float* __restrict__ istd) {
  const int c = threadIdx.x;
  float s = 0.f, ss = 0.f;
#pragma unroll
  for (int z = 0; z < 8; ++z) { s += out2[z * 256 + c]; ss += out2[2048 + z * 256 + c]; }
  float m = s * (1.f / 82944.f);
  float var = ss * (1.f / 82944.f) - m * m;
  mean[c] = m;
  istd[c] = rsqrtf(var + 1e-5f);
}

// ---- packed split-K f16 MFMA GEMM, 3-deep counted-vmcnt pipeline ----------
__global__ __launch_bounds__(256) void k_gemm_f16pk(
    const f16* __restrict__ Apk, const f16* __restrict__ Bpk,
    float* __restrict__ part, int K, int Nout, int stepsPerZ, int mrows) {
  __shared__ f16x8 sA[1536];
  __shared__ f16x8 sB[1536];
  const int nt = blockIdx.x, mt = blockIdx.y, z = blockIdx.z;
  const int tid = threadIdx.x;
  const int lane = tid & 63;
  const int wv = tid >> 6;
  const int wr = wv >> 1, wc = wv & 1;

  const f16* aC = Apk + (size_t)mt * K * 128 + wv * 1024 + lane * 8;
  const f16* bC = Bpk + (size_t)nt * K * 128 + wv * 1024 + lane * 8;
  const int loff = wv * 2048 + lane * 16;

  auto stage = [&](int buf, int ks) {
    char* lA = (char*)sA + buf * 8192 + loff;
    char* lB = (char*)sB + buf * 8192 + loff;
    const f16* ap = aC + (size_t)ks * 4096;
    const f16* bp = bC + (size_t)ks * 4096;
    gload16(ap, lA);
    gload16(ap + 512, lA + 1024);
    gload16(bp, lB);
    gload16(bp + 512, lB + 1024);
  };

  f32x4 acc[4][4] = {};
  const int fidxA = ((lane >> 4) << 7) + wr * 64 + (lane & 15);
  const int fidxB = ((lane >> 4) << 7) + wc * 64 + (lane & 15);

  const int ks0 = z * stepsPerZ;
  stage(0, ks0); stage(1, ks0 + 1); stage(2, ks0 + 2);
  int cur = 0;
  for (int i = 0; i < stepsPerZ; ++i) {
    const int r = stepsPerZ - 1 - i;
    if (r >= 2)      WAITB(8);
    else if (r == 1) WAITB(4);
    else             WAITB(0);
    const int base = cur * 512;
    f16x8 af[4], bf[4];
#pragma unroll
    for (int j = 0; j < 4; ++j) {
      af[j] = sA[base + fidxA + j * 16];
      bf[j] = sB[base + fidxB + j * 16];
    }
    __builtin_amdgcn_s_setprio(1);
#pragma unroll
    for (int ii = 0; ii < 4; ++ii)
#pragma unroll
      for (int jj = 0; jj < 4; ++jj)
        acc[ii][jj] = __builtin_amdgcn_mfma_f32_16x16x32_f16(af[ii], bf[jj], acc[ii][jj], 0, 0, 0);
    __builtin_amdgcn_s_setprio(0);
    LGKB();
    if (i + 3 < stepsPerZ) stage(cur, ks0 + i + 3);
    cur = (cur == 2) ? 0 : cur + 1;
  }

  const size_t zoff = (size_t)z * mrows * Nout;
  const int colb = nt * 128 + wc * 64 + (lane & 15);
  const int rowb = mt * 128 + wr * 64 + ((lane >> 4) << 2);
#pragma unroll
  for (int i = 0; i < 4; ++i)
#pragma unroll
    for (int j = 0; j < 4; ++j)
#pragma unroll
      for (int r = 0; r < 4; ++r)
        part[zoff + (size_t)(rowb + i * 16 + r) * Nout + colb + j * 16] = acc[i][j][r];
}

// ---- fused: reduce split-K partials + bias + FC BN partial stats ----------
__global__ void k_reduce_stats(const float* __restrict__ part, const float* __restrict__ bias,
                               float* __restrict__ out, int mrows, int Mout, int Nout,
                               int sk, int rpz,
                               float* __restrict__ psum, float* __restrict__ psq) {
  const int col = blockIdx.x * 256 + threadIdx.x;
  const int z = blockIdx.y;
  const float b = bias[col];
  float s = 0.f, ss = 0.f;
  const int r0 = z * rpz, r1 = min(Mout, r0 + rpz);
  for (int m = r0; m < r1; ++m) {
    float v = b;
    for (int zz = 0; zz < sk; ++zz)
      v += part[(size_t)zz * mrows * Nout + (size_t)m * Nout + col];
    out[(size_t)m * Nout + col] = v;
    s += v; ss += v * v;
  }
  psum[(size_t)z * Nout + col] = s;
  psq[(size_t)z * Nout + col] = ss;
}

// ---- PrRoI separable weights + sparse-range metadata ----------------------
__global__ void k_wxy(const float* __restrict__ rois, int ntot, int P,
                      float* __restrict__ Wx, float* __restrict__ Wy,
                      float* __restrict__ area,
                      int* __restrict__ HLO, int* __restrict__ HCNT,
                      int* __restrict__ WLO) {
  int idx = blockIdx.x * blockDim.x + threadIdx.x;
  if (idx >= ntot) return;
  float rx = rois[idx * 4 + 0], ry = rois[idx * 4 + 1];
  float rw = rois[idx * 4 + 2], rh = rois[idx * 4 + 3];
  float x1 = rx * 0.125f, y1 = ry * 0.125f;
  float x2 = (rx + rw) * 0.125f, y2 = (ry + rh) * 0.125f;
  float bw = (x2 - x1) / P, bh = (y2 - y1) / P;
  area[idx] = bw * bh;
  int hlo = max(0, (int)ceilf(y1 - 1.f));
  int hhi = min(35, (int)floorf(y2 + 1.f));
  HLO[idx] = hlo;
  HCNT[idx] = max(0, hhi - hlo + 1);
  for (int q = 0; q < P; ++q) {
    float xlo = x1 + q * bw, ylo = y1 + q * bh;
    WLO[idx * P + q] = min(31, max(0, (int)ceilf(xlo - 1.f)));
    for (int g = 0; g < 36; ++g) {
      float fg = (float)g;
      Wx[(idx * P + q) * 36 + g] = hat_int(xlo + bw - fg) - hat_int(xlo - fg);
      Wy[(idx * P + q) * 36 + g] = hat_int(ylo + bh - fg) - hat_int(ylo - fg);
    }
  }
}

// ---- PrRoI pool from HWC f16 with fused BN+ReLU, DENSE row-major output ---
template <int P, bool MOD>
__global__ __launch_bounds__(256) void k_pool(
    const f16* __restrict__ feat, const float* __restrict__ Wx,
    const float* __restrict__ Wy, const float* __restrict__ area,
    const int* __restrict__ HLO, const int* __restrict__ HCNT,
    const int* __restrict__ WLO,
    const float* __restrict__ mean, const float* __restrict__ istd,
    const float* __restrict__ g, const float* __restrict__ be,
    const float* __restrict__ mod, f16* __restrict__ out, int N) {
  const int s = blockIdx.x, n = blockIdx.y;
  const int idx = s * N + n;
  const int c = threadIdx.x;
  constexpr int KD = P * P * 256;
  __shared__ f16 sOut[KD];
  __shared__ float sWx[P * 36], sWy[P * 36];
  __shared__ int sWLO[P];
  __shared__ int sH[2];
  for (int i = threadIdx.x; i < P * 36; i += 256) {
    sWx[i] = Wx[(size_t)idx * P * 36 + i];
    sWy[i] = Wy[(size_t)idx * P * 36 + i];
  }
  if (threadIdx.x < P) sWLO[threadIdx.x] = WLO[idx * P + threadIdx.x];
  if (threadIdx.x == 0) { sH[0] = HLO[idx]; sH[1] = HCNT[idx]; }
  __syncthreads();
  const float sc = istd[c] * g[c];
  const float sh = be[c] - mean[c] * sc;
  const f16* f = feat + (size_t)s * 1296 * 256 + c;
  float o[P][P] = {};
  const int hlo = sH[0], hcnt = sH[1];
  for (int hh = 0; hh < hcnt; ++hh) {
    const int h = hlo + hh;
    const f16* rp = f + (size_t)h * 36 * 256;
    float colsum[P];
#pragma unroll
    for (int q = 0; q < P; ++q) {
      const int w0 = sWLO[q];
      const f16* wp = rp + (size_t)w0 * 256;
      float v = 0.f;
#pragma unroll
      for (int j = 0; j < 5; ++j) {
        float x = fmaxf(fmaf((float)wp[j * 256], sc, sh), 0.f);
        v = fmaf(sWx[q * 36 + w0 + j], x, v);
      }
      colsum[q] = v;
    }
#pragma unroll
    for (int p = 0; p < P; ++p) {
      const float wy = sWy[p * 36 + h];
      if (wy != 0.f) {
#pragma unroll
        for (int q = 0; q < P; ++q) o[p][q] = fmaf(wy, colsum[q], o[p][q]);
      }
    }
  }
  float a = area[idx];
  float inv = (a > 0.f) ? 1.f / fmaxf(a, 1e-12f) : 0.f;
  float msc = MOD ? (mod[s * 256 + c] * inv) : inv;
  const int kbase = c * (P * P);
#pragma unroll
  for (int p = 0; p < P; ++p)
#pragma unroll
    for (int q = 0; q < P; ++q)
      sOut[kbase + p * P + q] = (f16)(o[p][q] * msc);
  __syncthreads();
  f16* op = out + (size_t)idx * KD;
  for (int j = threadIdx.x; j < KD; j += 256) op[j] = sOut[j];
}

// ---- FC BN stats pass 2 ---------------------------------------------------
__global__ void k_fc_stats_final(const float* __restrict__ psum, const float* __restrict__ psq,
                                 int nz, int Nf, int M,
                                 float* __restrict__ mean, float* __restrict__ istd) {
  int col = blockIdx.x * 256 + threadIdx.x;
  if (col >= Nf) return;
  float s = 0.f, ss = 0.f;
  for (int z = 0; z < nz; ++z) {
    s += psum[(size_t)z * Nf + col];
    ss += psq[(size_t)z * Nf + col];
  }
  float mu = s / (float)M;
  float var = ss / (float)M - mu * mu;
  mean[col] = mu;
  istd[col] = rsqrtf(var + 1e-5f);
}

// ---- FC BN+ReLU elementwise (fp32 in place) -------------------------------
__global__ void k_fc_bn_relu(float* __restrict__ y, const float* __restrict__ mean,
                             const float* __restrict__ istd, const float* __restrict__ g,
                             const float* __restrict__ be, int total, int Nf) {
  int i = blockIdx.x * 256 + threadIdx.x;
  if (i >= total) return;
  int col = i % Nf;
  float sc = istd[col] * g[col];
  float sh = be[col] - mean[col] * sc;
  y[i] = fmaxf(fmaf(y[i], sc, sh), 0.f);
}

// ---- FC BN+ReLU -> packed f16; rows >= Mvalid write 0 (pad rows) ----------
__global__ void k_fc_bn_relu_pk(const float* __restrict__ y, const float* __restrict__ mean,
                                const float* __restrict__ istd, const float* __restrict__ g,
                                const float* __restrict__ be, f16* __restrict__ xpk,
                                int total, int Nf, int Mvalid) {
  int i = blockIdx.x * 256 + threadIdx.x;
  if (i >= total) return;
  int row = i / Nf, col = i - row * Nf;
  float v = 0.f;
  if (row < Mvalid) {
    float sc = istd[col] * g[col];
    float sh = be[col] - mean[col] * sc;
    v = fmaxf(fmaf(y[i], sc, sh), 0.f);
  }
  xpk[pk_off(row, col, Nf)] = (f16)v;
}

// ---- IoU head -------------------------------------------------------------
__global__ void k_iou(const float* __restrict__ x, const float* __restrict__ w,
                      const float* __restrict__ b, float* __restrict__ out) {
  const int r = blockIdx.x, tid = threadIdx.x;
  float s = 0.f;
  for (int k = tid; k < 1024; k += 256) s = fmaf(x[(size_t)r * 1024 + k], w[k], s);
  __shared__ float red[256];
  red[tid] = s;
  __syncthreads();
  for (int o = 128; o > 0; o >>= 1) {
    if (tid < o) red[tid] += red[tid + o];
    __syncthreads();
  }
  if (tid == 0) out[r] = red[0] + b[0];
}

// ---------------------------------------------------------------------------
// Workspace layout (float offsets). Same as round 16.
// ---------------------------------------------------------------------------
static const size_t O_A      = 0;
static const size_t O_POOLT  = 12000000;
static const size_t O_PSC2   = 12000000;
static const size_t O_PSC2B  = 12800000;
static const size_t O_PSUM   = 13000000;
static const size_t O_PSQ    = 13200000;
static const size_t O_WPK2RT = 16000000;
static const size_t O_POOLR  = 18500000;
static const size_t O_WPK2R  = 20000000;
static const size_t O_FT     = 21233664;
static const size_t O_X2PK   = 21233664 + 6422528;
static const size_t O_WC     = 33062912;
static const size_t O_WPK1RT = 33357824;
static const size_t O_WPK1R  = 39780352;
static const size_t O_PRPK   = 43057152;
static const size_t O_Y1     = 43466752;
static const size_t O_Y2     = 44515328;
static const size_t O_MOD    = 45563904;
static const size_t O_WXR    = 45580288;
static const size_t O_WYR    = 45591808;
static const size_t O_ARR    = 45603328;
static const size_t O_WXT    = 45603392;
static const size_t O_WYT    = 45861440;
static const size_t O_ART    = 46119488;
static const size_t O_MEAN   = 46120512;
static const size_t O_ISTD   = 46121536;
static const size_t O_X1PK   = 46122560;
static const size_t O_META   = 46188096;

extern "C" void kernel_launch(void* const* d_in, const int* in_sizes, int n_in,
                              void* d_out, int out_size, void* d_ws, size_t ws_size,
                              hipStream_t stream) {
  (void)in_sizes; (void)n_in; (void)out_size; (void)ws_size;
  const float* feat1  = (const float*)d_in[0];
  const float* feat2  = (const float*)d_in[1];
  const float* bb1    = (const float*)d_in[2];
  const float* props  = (const float*)d_in[3];
  const float* w_c1r  = (const float*)d_in[4];
  const float* b_c1r  = (const float*)d_in[5];
  const float* g_c1r  = (const float*)d_in[6];
  const float* be_c1r = (const float*)d_in[7];
  const float* w_c1t  = (const float*)d_in[8];
  const float* b_c1t  = (const float*)d_in[9];
  const float* g_c1t  = (const float*)d_in[10];
  const float* be_c1t = (const float*)d_in[11];
  const float* w_c2t  = (const float*)d_in[12];
  const float* b_c2t  = (const float*)d_in[13];
  const float* g_c2t  = (const float*)d_in[14];
  const float* be_c2t = (const float*)d_in[15];
  const float* w_f1r  = (const float*)d_in[16];
  const float* b_f1r  = (const float*)d_in[17];
  const float* g_f1r  = (const float*)d_in[18];
  const float* be_f1r = (const float*)d_in[19];
  const float* w_f2r  = (const float*)d_in[20];
  const float* b_f2r  = (const float*)d_in[21];
  const float* g_f2r  = (const float*)d_in[22];
  const float* be_f2r = (const float*)d_in[23];
  const float* w_f1rt = (const float*)d_in[24];
  const float* b_f1rt = (const float*)d_in[25];
  const float* g_f1rt = (const float*)d_in[26];
  const float* be_f1rt= (const float*)d_in[27];
  const float* w_f2rt = (const float*)d_in[28];
  const float* b_f2rt = (const float*)d_in[29];
  const float* g_f2rt = (const float*)d_in[30];
  const float* be_f2rt= (const float*)d_in[31];
  const float* w_iou  = (const float*)d_in[32];
  const float* b_iou  = (const float*)d_in[33];

  float* ws    = (float*)d_ws;
  f16*   AH    = (f16*)(ws + O_A);
  float* PART  = ws + O_A;
  f16*   POOLT = (f16*)(ws + O_POOLT);
  float* PSC2  = ws + O_PSC2;
  float* PSC2B = ws + O_PSC2B;
  float* PSUM  = ws + O_PSUM;
  float* PSQ   = ws + O_PSQ;
  f16*   WPK2RT= (f16*)(ws + O_WPK2RT);
  f16*   POOLR = (f16*)(ws + O_POOLR);
  f16*   WPK2R = (f16*)(ws + O_WPK2R);
  f16*   FT2   = (f16*)(ws + O_FT);
  f16*   PHPK  = FT2;
  f16*   X2PK  = (f16*)(ws + O_X2PK);
  f16*   WC    = (f16*)(ws + O_WC);
  f16*   WPK1RT= (f16*)(ws + O_WPK1RT);
  f16*   WPK1R = (f16*)(ws + O_WPK1R);
  f16*   PRPK  = (f16*)(ws + O_PRPK);
  float* Y1    = ws + O_Y1;
  float* Y2    = ws + O_Y2;
  float* MODp  = ws + O_MOD;
  float* WXR   = ws + O_WXR;
  float* WYR   = ws + O_WYR;
  float* ARR   = ws + O_ARR;
  float* WXT   = ws + O_WXT;
  float* WYT   = ws + O_WYT;
  float* ART   = ws + O_ART;
  float* MEAN  = ws + O_MEAN;
  float* ISTD  = ws + O_ISTD;
  f16*   X1PK  = (f16*)(ws + O_X1PK);
  int*   META  = (int*)(ws + O_META);
  int* HLOR = META;
  int* HCNTR= META + 64;
  int* WLOR = META + 128;
  int* HLOT = META + 448;
  int* HCNTT= META + 1472;
  int* WLOT = META + 2496;

  // ===== get_modulation branch =====
  k_pack_wc<<<2304, 256, 0, stream>>>(w_c1r, WC);
  k_padT<<<dim3(64, 32), 256, 0, stream>>>(feat1, FT2);
  k_conv_mfma<<<1408, 256, 0, stream>>>(WC, FT2, b_c1r, AH, PSC2);
  k_chan_fold8<<<8, 256, 0, stream>>>(PSC2, PSC2B);
  k_chan_final2<<<1, 256, 0, stream>>>(PSC2B, MEAN, ISTD);

  k_wxy<<<1, 64, 0, stream>>>(bb1, 64, 5, WXR, WYR, ARR, HLOR, HCNTR, WLOR);
  k_pool<5, false><<<dim3(64, 1), 256, 0, stream>>>(
      AH, WXR, WYR, ARR, HLOR, HCNTR, WLOR, MEAN, ISTD, g_c1r, be_c1r, nullptr, POOLR, 1);
  k_packx_h<<<dim3(25, 1), 256, 0, stream>>>(POOLR, PRPK, 64, 6400);

  k_packx_f<<<dim3(25, 8), 256, 0, stream>>>(w_f1r, WPK1R, 1024, 6400);
  k_gemm_f16pk<<<dim3(8, 1, 8), 256, 0, stream>>>(PRPK, WPK1R, PART, 6400, 1024, 25, 128);
  k_reduce_stats<<<dim3(4, 8), 256, 0, stream>>>(PART, b_f1r, Y1, 128, 64, 1024, 8, 8, PSUM, PSQ);
  k_fc_stats_final<<<4, 256, 0, stream>>>(PSUM, PSQ, 8, 1024, 64, MEAN, ISTD);
  k_fc_bn_relu_pk<<<512, 256, 0, stream>>>(Y1, MEAN, ISTD, g_f1r, be_f1r, X1PK, 128 * 1024, 1024, 64);

  k_packx_f<<<dim3(4, 2), 256, 0, stream>>>(w_f2r, WPK2R, 256, 1024);
  k_gemm_f16pk<<<dim3(2, 1, 4), 256, 0, stream>>>(X1PK, WPK2R, PART, 1024, 256, 8, 128);
  k_reduce_stats<<<dim3(1, 8), 256, 0, stream>>>(PART, b_f2r, MODp, 128, 64, 256, 4, 8, PSUM, PSQ);
  k_fc_stats_final<<<1, 256, 0, stream>>>(PSUM, PSQ, 8, 256, 64, MEAN, ISTD);
  k_fc_bn_relu<<<64, 256, 0, stream>>>(MODp, MEAN, ISTD, g_f2r, be_f2r, 64 * 256, 256);

  // ===== get_iou_feat branch =====
  k_pack_wc<<<2304, 256, 0, stream>>>(w_c1t, WC);
  k_padT<<<dim3(64, 32), 256, 0, stream>>>(feat2, FT2);
  k_conv_mfma<<<1408, 256, 0, stream>>>(WC, FT2, b_c1t, AH, PSC2);
  k_chan_fold8<<<8, 256, 0, stream>>>(PSC2, PSC2B);
  k_chan_final2<<<1, 256, 0, stream>>>(PSC2B, MEAN, ISTD);
  k_pad2<<<dim3(64, 36), 256, 0, stream>>>(AH, FT2, MEAN, ISTD, g_c1t, be_c1t);

  k_pack_wc<<<2304, 256, 0, stream>>>(w_c2t, WC);
  k_conv_mfma<<<1408, 256, 0, stream>>>(WC, FT2, b_c2t, AH, PSC2);
  k_chan_fold8<<<8, 256, 0, stream>>>(PSC2, PSC2B);
  k_chan_final2<<<1, 256, 0, stream>>>(PSC2B, MEAN, ISTD);

  // ===== predict_iou =====
  k_wxy<<<16, 64, 0, stream>>>(props, 1024, 7, WXT, WYT, ART, HLOT, HCNTT, WLOT);
  k_pool<7, true><<<dim3(64, 16), 256, 0, stream>>>(
      AH, WXT, WYT, ART, HLOT, HCNTT, WLOT, MEAN, ISTD, g_c2t, be_c2t, MODp, POOLT, 16);
  k_packx_h<<<dim3(49, 8), 256, 0, stream>>>(POOLT, PHPK, 1024, 12544);

  k_packx_f<<<dim3(49, 8), 256, 0, stream>>>(w_f1rt, WPK1RT, 1024, 12544);
  k_gemm_f16pk<<<dim3(8, 8, 8), 256, 0, stream>>>(PHPK, WPK1RT, PART, 12544, 1024, 49, 1024);
  k_reduce_stats<<<dim3(4, 128), 256, 0, stream>>>(PART, b_f1rt, Y1, 1024, 1024, 1024, 8, 8, PSUM, PSQ);
  k_fc_stats_final<<<4, 256, 0, stream>>>(PSUM, PSQ, 128, 1024, 1024, MEAN, ISTD);
  k_fc_bn_relu_pk<<<4096, 256, 0, stream>>>(Y1, MEAN, ISTD, g_f1rt, be_f1rt, X2PK, 1024 * 1024, 1024, 1024);

  k_packx_f<<<dim3(4, 8), 256, 0, stream>>>(w_f2rt, WPK2RT, 1024, 1024);
  k_gemm_f16pk<<<dim3(8, 8, 4), 256, 0, stream>>>(X2PK, WPK2RT, PART, 1024, 1024, 8, 1024);
  k_reduce_stats<<<dim3(4, 128), 256, 0, stream>>>(PART, b_f2rt, Y2, 1024, 1024, 1024, 4, 8, PSUM, PSQ);
  k_fc_stats_final<<<4, 256, 0, stream>>>(PSUM, PSQ, 128, 1024, 1024, MEAN, ISTD);
  k_fc_bn_relu<<<4096, 256, 0, stream>>>(Y2, MEAN, ISTD, g_f2rt, be_f2rt, 1024 * 1024, 1024);

  k_iou<<<1024, 256, 0, stream>>>(Y2, w_iou, b_iou, (float*)d_out);
}

// Round 18
// 884.136 us; speedup vs baseline: 1.0119x; 1.0119x over previous
//
#include <hip/hip_runtime.h>
#include <cstddef>

// ---------------------------------------------------------------------------
// FPNIoUNetHR forward — round 18: LOCK-IN of round-16 best configuration
// (884.6 us). Single-barrier conv K-step (4 B-buffers, restage last-consumed
// buffer), A-operand in registers via asm loads, 36 KB LDS, single-pass
// epilogue with fused BN stats. r17's 32KB/two-pass epilogue regressed and
// is reverted. S=64, C=256, H=W=36, N=16.
// ---------------------------------------------------------------------------

typedef _Float16 f16;
typedef __attribute__((ext_vector_type(8))) _Float16 f16x8;
typedef __attribute__((ext_vector_type(4))) float f32x4;

__device__ __forceinline__ void gload16(const void* g, void* l) {
  __builtin_amdgcn_global_load_lds((const __attribute__((address_space(1))) void*)g,
                                   (__attribute__((address_space(3))) void*)l, 16, 0, 0);
}

// async global->VGPR load invisible to the compiler's waitcnt pass.
__device__ __forceinline__ f16x8 gload_reg(const f16* p) {
  f16x8 v;
  asm volatile("global_load_dwordx4 %0, %1, off" : "=&v"(v) : "v"(p) : "memory");
  return v;
}

#define WAITB(N) asm volatile("s_waitcnt vmcnt(" #N ")\n\ts_barrier" ::: "memory")
#define LGKB()   asm volatile("s_waitcnt lgkmcnt(0)\n\ts_barrier" ::: "memory")

static __device__ __forceinline__ float hat_int(float x) {
  float u = fminf(1.f, fmaxf(-1.f, x));
  float a = 0.5f * (1.f + u) * (1.f + u);
  float b = 0.5f + u - 0.5f * u * u;
  return (u <= 0.f) ? a : b;
}

// Packed GEMM operand layout: element (row,k) of a row-major [M][K] matrix ->
// [row/128][k/32][(k/8)%4][row%128][k%8]. One k-step chunk (128 rows x 32 k)
// is 8 KB contiguous, exactly the LDS image the MFMA frag reads want.
static __device__ __forceinline__ size_t pk_off(int row, int k, int K) {
  return (size_t)(row >> 7) * ((size_t)K * 128) + (size_t)(k >> 5) * 4096
       + (size_t)((((k >> 3) & 3) * 128 + (row & 127)) * 8 + (k & 7));
}

// ---- coalesced pad: fp32 CHW input -> FT2 f16, LDS transpose --------------
__global__ __launch_bounds__(256) void k_padT(const float* __restrict__ src,
                                              f16* __restrict__ FT) {
  __shared__ f16 sT[8][1300];
  const int img = blockIdx.x, kk = blockIdx.y;
  const float* sp = src + ((size_t)img * 256 + kk * 8) * 1296;
#pragma unroll
  for (int c = 0; c < 8; ++c)
    for (int i = threadIdx.x; i < 1296; i += 256)
      sT[c][i] = (f16)sp[c * 1296 + i];
  __syncthreads();
  f16* op = FT + ((size_t)img * 32 + kk) * 1444 * 8;
  for (int i = threadIdx.x; i < 148; i += 256) {
    int r, cc;
    if (i < 38)       { r = 0;          cc = i; }
    else if (i < 76)  { r = 37;         cc = i - 38; }
    else if (i < 112) { r = i - 76 + 1; cc = 0; }
    else              { r = i - 112 + 1; cc = 37; }
    f16x8 z = {};
    *reinterpret_cast<f16x8*>(op + (r * 38 + cc) * 8) = z;
  }
  for (int i = threadIdx.x; i < 1296; i += 256) {
    const int h = i / 36, w = i - h * 36;
    f16x8 v;
#pragma unroll
    for (int c = 0; c < 8; ++c) v[c] = sT[c][i];
    *reinterpret_cast<f16x8*>(op + ((h + 1) * 38 + w + 1) * 8) = v;
  }
}

// ---- pad HWC f16 conv output + BN+ReLU -> FT2 f16 -------------------------
__global__ void k_pad2(const f16* __restrict__ yH, f16* __restrict__ FT,
                       const float* __restrict__ mean, const float* __restrict__ istd,
                       const float* __restrict__ g, const float* __restrict__ be) {
  const int img = blockIdx.x, h = blockIdx.y, c = threadIdx.x;
  const float sc = istd[c] * g[c];
  const float sh = be[c] - mean[c] * sc;
  const f16* sp = yH + ((size_t)img * 1296 + h * 36) * 256 + c;
  f16* op = FT + (((size_t)img * 32 + (c >> 3)) * 1444 + (h + 1) * 38 + 1) * 8 + (c & 7);
#pragma unroll 4
  for (int w = 0; w < 36; ++w) {
    float v = fmaxf(fmaf((float)sp[w * 256], sc, sh), 0.f);
    op[w * 8] = (f16)v;
  }
}

// ---- conv weights [256][256][3][3] fp32 -> packed f16 ---------------------
__global__ void k_pack_wc(const float* __restrict__ w, f16* __restrict__ dst) {
  int i = blockIdx.x * 256 + threadIdx.x;   // < 589,824
  int oct = i / 294912;
  int r = i - oct * 294912;
  int ks = r >> 12;
  int r2 = r & 4095;
  int koct = r2 >> 10;
  int r3 = r2 & 1023;
  int row = r3 >> 3, kj = r3 & 7;
  int k = ks * 32 + koct * 8 + kj;
  int t = k >> 8, c = k & 255;
  int oc = oct * 128 + row;
  dst[i] = (f16)w[(oc * 256 + c) * 9 + t];
}

// ---- tiled LDS transpose: row-major [M][K] -> pk layout (zero-fill) -------
__global__ __launch_bounds__(256) void k_packx_h(
    const f16* __restrict__ src, f16* __restrict__ dst, int M, int K) {
  __shared__ f16 sT[128][264];
  const int k0 = blockIdx.x * 256, r0 = blockIdx.y * 128;
  const int t = threadIdx.x;
  const int rl = t >> 5, kk = (t & 31) * 8;
  for (int rnd = 0; rnd < 16; ++rnd) {
    const int row_l = rl + rnd * 8;
    const int row = r0 + row_l;
    if (row < M) {
      f16x8 v = *reinterpret_cast<const f16x8*>(src + (size_t)row * K + k0 + kk);
      *reinterpret_cast<f16x8*>(&sT[row_l][kk]) = v;
    }
  }
  __syncthreads();
  const size_t base = (size_t)(r0 >> 7) * ((size_t)K * 128) + (size_t)(k0 >> 5) * 4096;
#pragma unroll
  for (int cs = 0; cs < 8; ++cs) {
#pragma unroll
    for (int half = 0; half < 2; ++half) {
      const int e = half * 256 + t;
      const int koct = e >> 7, row_l = e & 127;
      f16x8 v = {};
      if (r0 + row_l < M)
        v = *reinterpret_cast<const f16x8*>(&sT[row_l][cs * 32 + koct * 8]);
      *reinterpret_cast<f16x8*>(dst + base + (size_t)cs * 4096 + e * 8) = v;
    }
  }
}

__global__ __launch_bounds__(256) void k_packx_f(
    const float* __restrict__ src, f16* __restrict__ dst, int M, int K) {
  __shared__ f16 sT[128][264];
  const int k0 = blockIdx.x * 256, r0 = blockIdx.y * 128;
  const int t = threadIdx.x;
  const int rl = t >> 5, kk = (t & 31) * 8;
  for (int rnd = 0; rnd < 16; ++rnd) {
    const int row_l = rl + rnd * 8;
    const int row = r0 + row_l;
    if (row < M) {
      const float4* sp = reinterpret_cast<const float4*>(src + (size_t)row * K + k0 + kk);
      float4 a = sp[0], b = sp[1];
      f16* o = &sT[row_l][kk];
      o[0] = (f16)a.x; o[1] = (f16)a.y; o[2] = (f16)a.z; o[3] = (f16)a.w;
      o[4] = (f16)b.x; o[5] = (f16)b.y; o[6] = (f16)b.z; o[7] = (f16)b.w;
    }
  }
  __syncthreads();
  const size_t base = (size_t)(r0 >> 7) * ((size_t)K * 128) + (size_t)(k0 >> 5) * 4096;
#pragma unroll
  for (int cs = 0; cs < 8; ++cs) {
#pragma unroll
    for (int half = 0; half < 2; ++half) {
      const int e = half * 256 + t;
      const int koct = e >> 7, row_l = e & 127;
      f16x8 v = {};
      if (r0 + row_l < M)
        v = *reinterpret_cast<const f16x8*>(&sT[row_l][cs * 32 + koct * 8]);
      *reinterpret_cast<f16x8*>(dst + base + (size_t)cs * 4096 + e * 8) = v;
    }
  }
}

// ---- 3x3 conv: A in regs (asm), B via 4 LDS bufs, ONE barrier per step ----
// Restage targets the buffer consumed LAST step: before any wave passes the
// step-ks barrier it issued step-(ks-1) MFMAs, whose compiler lgkmcnt waits
// retired those ds_reads -> restage write cannot race a read.
__global__ __launch_bounds__(256, 2) void k_conv_mfma(
    const f16* __restrict__ Wpk, const f16* __restrict__ FT2,
    const float* __restrict__ bias, f16* __restrict__ yH,
    float* __restrict__ psc) {
  __shared__ __align__(16) char smem[36864];   // sB 4x8KB; epilogue 34.8KB
  f16x8* sB = (f16x8*)smem;            // 4 buffers x 512
  const int bid = blockIdx.x;
  const int orig = (bid & 7) * 176 + (bid >> 3);   // bijective: 1408 % 8 == 0
  const int img = orig / 22;
  const int rem = orig - img * 22;
  const int oct = rem / 11;
  const int pt  = rem - oct * 11;
  const int m0 = oct * 128;
  const int p0 = pt * 128;
  const int tid = threadIdx.x;
  const int lane = tid & 63;
  const int wv = tid >> 6;
  const int wr = wv >> 1, wc = wv & 1;

  const f16* aFrag = Wpk + (size_t)oct * 294912 + ((lane >> 4) << 10)
                   + ((size_t)(wr * 64 + (lane & 15)) << 3);
  const f16* ftImg = FT2 + (size_t)img * 32 * 1444 * 8;
  int pos0 = p0 + lane;
  int pc0 = min(pos0, 1295);
  int pc1 = min(pos0 + 64, 1295);
  int pb0 = (pc0 / 36) * 38 + (pc0 % 36);
  int pb1 = (pc1 / 36) * 38 + (pc1 % 36);

  const int loff = wv * 2048 + lane * 16;

  auto stageB = [&](int buf, int ks) {
    const int t = ks >> 3;
    const int dy = t / 3, dx = t - dy * 3;
    const int cs = ks & 7;
    const int dyx = dy * 38 + dx;
    char* lB = (char*)sB + buf * 8192 + loff;
    const f16* bp = ftImg + ((size_t)(cs * 4 + wv) * 1444 + dyx) * 8;
    gload16(bp + pb0 * 8, lB);
    gload16(bp + pb1 * 8, lB + 1024);
  };

#define LOADA(ASET, KS)                                                        \
  {                                                                            \
    const f16* _p = aFrag + (size_t)(KS) * 4096;                               \
    ASET[0] = gload_reg(_p);                                                   \
    ASET[1] = gload_reg(_p + 128);                                             \
    ASET[2] = gload_reg(_p + 256);                                             \
    ASET[3] = gload_reg(_p + 384);                                             \
  }

  f32x4 acc[4][4] = {};
  const int fidxB = ((lane >> 4) << 7) + wc * 64 + (lane & 15);
  f16x8 A0[4], A1[4], A2[4];

  stageB(0, 0); LOADA(A0, 0);
  stageB(1, 1); LOADA(A1, 1);
  stageB(2, 2); LOADA(A2, 2);   // 18 VMEM ops in flight per wave

#define CSTEP(ASET, BUF, RBUF, KS)                                             \
  {                                                                            \
    const int rr = 71 - (KS);                                                  \
    if (rr >= 2)      WAITB(12);                                               \
    else if (rr == 1) WAITB(6);                                                \
    else              WAITB(0);                                                \
    __builtin_amdgcn_sched_barrier(0);                                         \
    f16x8 bf[4];                                                               \
    _Pragma("unroll") for (int j = 0; j < 4; ++j)                              \
      bf[j] = sB[(BUF) * 512 + fidxB + j * 16];                                \
    __builtin_amdgcn_s_setprio(1);                                             \
    _Pragma("unroll") for (int ii = 0; ii < 4; ++ii)                           \
      _Pragma("unroll") for (int jj = 0; jj < 4; ++jj)                         \
        acc[ii][jj] = __builtin_amdgcn_mfma_f32_16x16x32_f16(ASET[ii], bf[jj], acc[ii][jj], 0, 0, 0); \
    __builtin_amdgcn_s_setprio(0);                                             \
    if ((KS) + 3 < 72) { stageB(RBUF, (KS) + 3); LOADA(ASET, (KS) + 3); }      \
  }

  for (int ks = 0; ks < 72; ks += 12) {
    CSTEP(A0, 0, 3, ks);
    CSTEP(A1, 1, 0, ks + 1);
    CSTEP(A2, 2, 1, ks + 2);
    CSTEP(A0, 3, 2, ks + 3);
    CSTEP(A1, 0, 3, ks + 4);
    CSTEP(A2, 1, 0, ks + 5);
    CSTEP(A0, 2, 1, ks + 6);
    CSTEP(A1, 3, 2, ks + 7);
    CSTEP(A2, 0, 3, ks + 8);
    CSTEP(A0, 1, 0, ks + 9);
    CSTEP(A1, 2, 1, ks + 10);
    CSTEP(A2, 3, 2, ks + 11);
  }
#undef CSTEP
#undef LOADA

  // ---- epilogue: acc -> LDS [128 pos][128 oc] (+pad) -> coalesced stores --
  __syncthreads();
  f16* sE = (f16*)smem;                 // 128 x 136 f16 = 34.8 KB
  const int ocl = wr * 64 + ((lane >> 4) << 2);
#pragma unroll
  for (int i = 0; i < 4; ++i) {
    const int oc0 = m0 + ocl + i * 16;
    float b0 = bias[oc0], b1 = bias[oc0 + 1], b2 = bias[oc0 + 2], b3 = bias[oc0 + 3];
#pragma unroll
    for (int j = 0; j < 4; ++j) {
      f16* e = &sE[(wc * 64 + j * 16 + (lane & 15)) * 136 + ocl + i * 16];
      e[0] = (f16)(acc[i][j][0] + b0);
      e[1] = (f16)(acc[i][j][1] + b1);
      e[2] = (f16)(acc[i][j][2] + b2);
      e[3] = (f16)(acc[i][j][3] + b3);
    }
  }
  __syncthreads();
  f16* yb = yH + (size_t)img * 1296 * 256 + m0;
#pragma unroll
  for (int it = 0; it < 8; ++it) {
    const int e = (it * 256 + tid) * 8;
    const int row = e >> 7;
    const int oc = e & 127;
    const int col = p0 + row;
    if (col < 1296)
      *reinterpret_cast<f16x8*>(yb + (size_t)col * 256 + oc) =
        *reinterpret_cast<const f16x8*>(&sE[row * 136 + oc]);
  }
  // ---- channel stats partials: 256 threads = 2 row-halves x 128 oc --------
  const int nvalid = min(128, 1296 - p0);
  const int half = tid >> 7, cc = tid & 127;
  const int r0 = half * 64, r1 = min(nvalid, r0 + 64);
  float s = 0.f, ss = 0.f;
  for (int row = r0; row < r1; ++row) {
    float v = (float)sE[row * 136 + cc];
    s += v; ss += v * v;
  }
  const int bi = (half * 704 + img * 11 + pt) * 256 + m0 + cc;
  psc[bi] = s;
  psc[360448 + bi] = ss;
}

// ---- fold conv stats partials: 1408 entries -> 8 -> mean/istd -------------
__global__ void k_chan_fold8(const float* __restrict__ psc, float* __restrict__ out2) {
  const int z = blockIdx.x, c = threadIdx.x;
  float s = 0.f, ss = 0.f;
  for (int i = z * 176; i < z * 176 + 176; ++i) {
    s += psc[i * 256 + c];
    ss += psc[360448 + i * 256 + c];
  }
  out2[z * 256 + c] = s;
  out2[2048 + z * 256 + c] = ss;
}

__global__ void k_chan_final2(const float* __restrict__ out2,
                              float* __restrict__ mean, float* __restrict__ istd) {
  const int c = threadIdx.x;
  float s = 0.f, ss = 0.f;
#pragma unroll
  for (int z = 0; z < 8; ++z) { s += out2[z * 256 + c]; ss += out2[2048 + z * 256 + c]; }
  float m = s * (1.f / 82944.f);
  float var = ss * (1.f / 82944.f) - m * m;
  mean[c] = m;
  istd[c] = rsqrtf(var + 1e-5f);
}

// ---- packed split-K f16 MFMA GEMM, 3-deep counted-vmcnt pipeline ----------
__global__ __launch_bounds__(256) void k_gemm_f16pk(
    const f16* __restrict__ Apk, const f16* __restrict__ Bpk,
    float* __restrict__ part, int K, int Nout, int stepsPerZ, int mrows) {
  __shared__ f16x8 sA[1536];
  __shared__ f16x8 sB[1536];
  const int nt = blockIdx.x, mt = blockIdx.y, z = blockIdx.z;
  const int tid = threadIdx.x;
  const int lane = tid & 63;
  const int wv = tid >> 6;
  const int wr = wv >> 1, wc = wv & 1;

  const f16* aC = Apk + (size_t)mt * K * 128 + wv * 1024 + lane * 8;
  const f16* bC = Bpk + (size_t)nt * K * 128 + wv * 1024 + lane * 8;
  const int loff = wv * 2048 + lane * 16;

  auto stage = [&](int buf, int ks) {
    char* lA = (char*)sA + buf * 8192 + loff;
    char* lB = (char*)sB + buf * 8192 + loff;
    const f16* ap = aC + (size_t)ks * 4096;
    const f16* bp = bC + (size_t)ks * 4096;
    gload16(ap, lA);
    gload16(ap + 512, lA + 1024);
    gload16(bp, lB);
    gload16(bp + 512, lB + 1024);
  };

  f32x4 acc[4][4] = {};
  const int fidxA = ((lane >> 4) << 7) + wr * 64 + (lane & 15);
  const int fidxB = ((lane >> 4) << 7) + wc * 64 + (lane & 15);

  const int ks0 = z * stepsPerZ;
  stage(0, ks0); stage(1, ks0 + 1); stage(2, ks0 + 2);
  int cur = 0;
  for (int i = 0; i < stepsPerZ; ++i) {
    const int r = stepsPerZ - 1 - i;
    if (r >= 2)      WAITB(8);
    else if (r == 1) WAITB(4);
    else             WAITB(0);
    const int base = cur * 512;
    f16x8 af[4], bf[4];
#pragma unroll
    for (int j = 0; j < 4; ++j) {
      af[j] = sA[base + fidxA + j * 16];
      bf[j] = sB[base + fidxB + j * 16];
    }
    __builtin_amdgcn_s_setprio(1);
#pragma unroll
    for (int ii = 0; ii < 4; ++ii)
#pragma unroll
      for (int jj = 0; jj < 4; ++jj)
        acc[ii][jj] = __builtin_amdgcn_mfma_f32_16x16x32_f16(af[ii], bf[jj], acc[ii][jj], 0, 0, 0);
    __builtin_amdgcn_s_setprio(0);
    LGKB();
    if (i + 3 < stepsPerZ) stage(cur, ks0 + i + 3);
    cur = (cur == 2) ? 0 : cur + 1;
  }

  const size_t zoff = (size_t)z * mrows * Nout;
  const int colb = nt * 128 + wc * 64 + (lane & 15);
  const int rowb = mt * 128 + wr * 64 + ((lane >> 4) << 2);
#pragma unroll
  for (int i = 0; i < 4; ++i)
#pragma unroll
    for (int j = 0; j < 4; ++j)
#pragma unroll
      for (int r = 0; r < 4; ++r)
        part[zoff + (size_t)(rowb + i * 16 + r) * Nout + colb + j * 16] = acc[i][j][r];
}

// ---- fused: reduce split-K partials + bias + FC BN partial stats ----------
__global__ void k_reduce_stats(const float* __restrict__ part, const float* __restrict__ bias,
                               float* __restrict__ out, int mrows, int Mout, int Nout,
                               int sk, int rpz,
                               float* __restrict__ psum, float* __restrict__ psq) {
  const int col = blockIdx.x * 256 + threadIdx.x;
  const int z = blockIdx.y;
  const float b = bias[col];
  float s = 0.f, ss = 0.f;
  const int r0 = z * rpz, r1 = min(Mout, r0 + rpz);
  for (int m = r0; m < r1; ++m) {
    float v = b;
    for (int zz = 0; zz < sk; ++zz)
      v += part[(size_t)zz * mrows * Nout + (size_t)m * Nout + col];
    out[(size_t)m * Nout + col] = v;
    s += v; ss += v * v;
  }
  psum[(size_t)z * Nout + col] = s;
  psq[(size_t)z * Nout + col] = ss;
}

// ---- PrRoI separable weights + sparse-range metadata ----------------------
__global__ void k_wxy(const float* __restrict__ rois, int ntot, int P,
                      float* __restrict__ Wx, float* __restrict__ Wy,
                      float* __restrict__ area,
                      int* __restrict__ HLO, int* __restrict__ HCNT,
                      int* __restrict__ WLO) {
  int idx = blockIdx.x * blockDim.x + threadIdx.x;
  if (idx >= ntot) return;
  float rx = rois[idx * 4 + 0], ry = rois[idx * 4 + 1];
  float rw = rois[idx * 4 + 2], rh = rois[idx * 4 + 3];
  float x1 = rx * 0.125f, y1 = ry * 0.125f;
  float x2 = (rx + rw) * 0.125f, y2 = (ry + rh) * 0.125f;
  float bw = (x2 - x1) / P, bh = (y2 - y1) / P;
  area[idx] = bw * bh;
  int hlo = max(0, (int)ceilf(y1 - 1.f));
  int hhi = min(35, (int)floorf(y2 + 1.f));
  HLO[idx] = hlo;
  HCNT[idx] = max(0, hhi - hlo + 1);
  for (int q = 0; q < P; ++q) {
    float xlo = x1 + q * bw, ylo = y1 + q * bh;
    WLO[idx * P + q] = min(31, max(0, (int)ceilf(xlo - 1.f)));
    for (int g = 0; g < 36; ++g) {
      float fg = (float)g;
      Wx[(idx * P + q) * 36 + g] = hat_int(xlo + bw - fg) - hat_int(xlo - fg);
      Wy[(idx * P + q) * 36 + g] = hat_int(ylo + bh - fg) - hat_int(ylo - fg);
    }
  }
}

// ---- PrRoI pool from HWC f16 with fused BN+ReLU, DENSE row-major output ---
template <int P, bool MOD>
__global__ __launch_bounds__(256) void k_pool(
    const f16* __restrict__ feat, const float* __restrict__ Wx,
    const float* __restrict__ Wy, const float* __restrict__ area,
    const int* __restrict__ HLO, const int* __restrict__ HCNT,
    const int* __restrict__ WLO,
    const float* __restrict__ mean, const float* __restrict__ istd,
    const float* __restrict__ g, const float* __restrict__ be,
    const float* __restrict__ mod, f16* __restrict__ out, int N) {
  const int s = blockIdx.x, n = blockIdx.y;
  const int idx = s * N + n;
  const int c = threadIdx.x;
  constexpr int KD = P * P * 256;
  __shared__ f16 sOut[KD];
  __shared__ float sWx[P * 36], sWy[P * 36];
  __shared__ int sWLO[P];
  __shared__ int sH[2];
  for (int i = threadIdx.x; i < P * 36; i += 256) {
    sWx[i] = Wx[(size_t)idx * P * 36 + i];
    sWy[i] = Wy[(size_t)idx * P * 36 + i];
  }
  if (threadIdx.x < P) sWLO[threadIdx.x] = WLO[idx * P + threadIdx.x];
  if (threadIdx.x == 0) { sH[0] = HLO[idx]; sH[1] = HCNT[idx]; }
  __syncthreads();
  const float sc = istd[c] * g[c];
  const float sh = be[c] - mean[c] * sc;
  const f16* f = feat + (size_t)s * 1296 * 256 + c;
  float o[P][P] = {};
  const int hlo = sH[0], hcnt = sH[1];
  for (int hh = 0; hh < hcnt; ++hh) {
    const int h = hlo + hh;
    const f16* rp = f + (size_t)h * 36 * 256;
    float colsum[P];
#pragma unroll
    for (int q = 0; q < P; ++q) {
      const int w0 = sWLO[q];
      const f16* wp = rp + (size_t)w0 * 256;
      float v = 0.f;
#pragma unroll
      for (int j = 0; j < 5; ++j) {
        float x = fmaxf(fmaf((float)wp[j * 256], sc, sh), 0.f);
        v = fmaf(sWx[q * 36 + w0 + j], x, v);
      }
      colsum[q] = v;
    }
#pragma unroll
    for (int p = 0; p < P; ++p) {
      const float wy = sWy[p * 36 + h];
      if (wy != 0.f) {
#pragma unroll
        for (int q = 0; q < P; ++q) o[p][q] = fmaf(wy, colsum[q], o[p][q]);
      }
    }
  }
  float a = area[idx];
  float inv = (a > 0.f) ? 1.f / fmaxf(a, 1e-12f) : 0.f;
  float msc = MOD ? (mod[s * 256 + c] * inv) : inv;
  const int kbase = c * (P * P);
#pragma unroll
  for (int p = 0; p < P; ++p)
#pragma unroll
    for (int q = 0; q < P; ++q)
      sOut[kbase + p * P + q] = (f16)(o[p][q] * msc);
  __syncthreads();
  f16* op = out + (size_t)idx * KD;
  for (int j = threadIdx.x; j < KD; j += 256) op[j] = sOut[j];
}

// ---- FC BN stats pass 2 ---------------------------------------------------
__global__ void k_fc_stats_final(const float* __restrict__ psum, const float* __restrict__ psq,
                                 int nz, int Nf, int M,
                                 float* __restrict__ mean, float* __restrict__ istd) {
  int col = blockIdx.x * 256 + threadIdx.x;
  if (col >= Nf) return;
  float s = 0.f, ss = 0.f;
  for (int z = 0; z < nz; ++z) {
    s += psum[(size_t)z * Nf + col];
    ss += psq[(size_t)z * Nf + col];
  }
  float mu = s / (float)M;
  float var = ss / (float)M - mu * mu;
  mean[col] = mu;
  istd[col] = rsqrtf(var + 1e-5f);
}

// ---- FC BN+ReLU elementwise (fp32 in place) -------------------------------
__global__ void k_fc_bn_relu(float* __restrict__ y, const float* __restrict__ mean,
                             const float* __restrict__ istd, const float* __restrict__ g,
                             const float* __restrict__ be, int total, int Nf) {
  int i = blockIdx.x * 256 + threadIdx.x;
  if (i >= total) return;
  int col = i % Nf;
  float sc = istd[col] * g[col];
  float sh = be[col] - mean[col] * sc;
  y[i] = fmaxf(fmaf(y[i], sc, sh), 0.f);
}

// ---- FC BN+ReLU -> packed f16; rows >= Mvalid write 0 (pad rows) ----------
__global__ void k_fc_bn_relu_pk(const float* __restrict__ y, const float* __restrict__ mean,
                                const float* __restrict__ istd, const float* __restrict__ g,
                                const float* __restrict__ be, f16* __restrict__ xpk,
                                int total, int Nf, int Mvalid) {
  int i = blockIdx.x * 256 + threadIdx.x;
  if (i >= total) return;
  int row = i / Nf, col = i - row * Nf;
  float v = 0.f;
  if (row < Mvalid) {
    float sc = istd[col] * g[col];
    float sh = be[col] - mean[col] * sc;
    v = fmaxf(fmaf(y[i], sc, sh), 0.f);
  }
  xpk[pk_off(row, col, Nf)] = (f16)v;
}

// ---- IoU head -------------------------------------------------------------
__global__ void k_iou(const float* __restrict__ x, const float* __restrict__ w,
                      const float* __restrict__ b, float* __restrict__ out) {
  const int r = blockIdx.x, tid = threadIdx.x;
  float s = 0.f;
  for (int k = tid; k < 1024; k += 256) s = fmaf(x[(size_t)r * 1024 + k], w[k], s);
  __shared__ float red[256];
  red[tid] = s;
  __syncthreads();
  for (int o = 128; o > 0; o >>= 1) {
    if (tid < o) red[tid] += red[tid + o];
    __syncthreads();
  }
  if (tid == 0) out[r] = red[0] + b[0];
}

// ---------------------------------------------------------------------------
// Workspace layout (float offsets). Same as round 16.
// ---------------------------------------------------------------------------
static const size_t O_A      = 0;
static const size_t O_POOLT  = 12000000;
static const size_t O_PSC2   = 12000000;
static const size_t O_PSC2B  = 12800000;
static const size_t O_PSUM   = 13000000;
static const size_t O_PSQ    = 13200000;
static const size_t O_WPK2RT = 16000000;
static const size_t O_POOLR  = 18500000;
static const size_t O_WPK2R  = 20000000;
static const size_t O_FT     = 21233664;
static const size_t O_X2PK   = 21233664 + 6422528;
static const size_t O_WC     = 33062912;
static const size_t O_WPK1RT = 33357824;
static const size_t O_WPK1R  = 39780352;
static const size_t O_PRPK   = 43057152;
static const size_t O_Y1     = 43466752;
static const size_t O_Y2     = 44515328;
static const size_t O_MOD    = 45563904;
static const size_t O_WXR    = 45580288;
static const size_t O_WYR    = 45591808;
static const size_t O_ARR    = 45603328;
static const size_t O_WXT    = 45603392;
static const size_t O_WYT    = 45861440;
static const size_t O_ART    = 46119488;
static const size_t O_MEAN   = 46120512;
static const size_t O_ISTD   = 46121536;
static const size_t O_X1PK   = 46122560;
static const size_t O_META   = 46188096;

extern "C" void kernel_launch(void* const* d_in, const int* in_sizes, int n_in,
                              void* d_out, int out_size, void* d_ws, size_t ws_size,
                              hipStream_t stream) {
  (void)in_sizes; (void)n_in; (void)out_size; (void)ws_size;
  const float* feat1  = (const float*)d_in[0];
  const float* feat2  = (const float*)d_in[1];
  const float* bb1    = (const float*)d_in[2];
  const float* props  = (const float*)d_in[3];
  const float* w_c1r  = (const float*)d_in[4];
  const float* b_c1r  = (const float*)d_in[5];
  const float* g_c1r  = (const float*)d_in[6];
  const float* be_c1r = (const float*)d_in[7];
  const float* w_c1t  = (const float*)d_in[8];
  const float* b_c1t  = (const float*)d_in[9];
  const float* g_c1t  = (const float*)d_in[10];
  const float* be_c1t = (const float*)d_in[11];
  const float* w_c2t  = (const float*)d_in[12];
  const float* b_c2t  = (const float*)d_in[13];
  const float* g_c2t  = (const float*)d_in[14];
  const float* be_c2t = (const float*)d_in[15];
  const float* w_f1r  = (const float*)d_in[16];
  const float* b_f1r  = (const float*)d_in[17];
  const float* g_f1r  = (const float*)d_in[18];
  const float* be_f1r = (const float*)d_in[19];
  const float* w_f2r  = (const float*)d_in[20];
  const float* b_f2r  = (const float*)d_in[21];
  const float* g_f2r  = (const float*)d_in[22];
  const float* be_f2r = (const float*)d_in[23];
  const float* w_f1rt = (const float*)d_in[24];
  const float* b_f1rt = (const float*)d_in[25];
  const float* g_f1rt = (const float*)d_in[26];
  const float* be_f1rt= (const float*)d_in[27];
  const float* w_f2rt = (const float*)d_in[28];
  const float* b_f2rt = (const float*)d_in[29];
  const float* g_f2rt = (const float*)d_in[30];
  const float* be_f2rt= (const float*)d_in[31];
  const float* w_iou  = (const float*)d_in[32];
  const float* b_iou  = (const float*)d_in[33];

  float* ws    = (float*)d_ws;
  f16*   AH    = (f16*)(ws + O_A);
  float* PART  = ws + O_A;
  f16*   POOLT = (f16*)(ws + O_POOLT);
  float* PSC2  = ws + O_PSC2;
  float* PSC2B = ws + O_PSC2B;
  float* PSUM  = ws + O_PSUM;
  float* PSQ   = ws + O_PSQ;
  f16*   WPK2RT= (f16*)(ws + O_WPK2RT);
  f16*   POOLR = (f16*)(ws + O_POOLR);
  f16*   WPK2R = (f16*)(ws + O_WPK2R);
  f16*   FT2   = (f16*)(ws + O_FT);
  f16*   PHPK  = FT2;
  f16*   X2PK  = (f16*)(ws + O_X2PK);
  f16*   WC    = (f16*)(ws + O_WC);
  f16*   WPK1RT= (f16*)(ws + O_WPK1RT);
  f16*   WPK1R = (f16*)(ws + O_WPK1R);
  f16*   PRPK  = (f16*)(ws + O_PRPK);
  float* Y1    = ws + O_Y1;
  float* Y2    = ws + O_Y2;
  float* MODp  = ws + O_MOD;
  float* WXR   = ws + O_WXR;
  float* WYR   = ws + O_WYR;
  float* ARR   = ws + O_ARR;
  float* WXT   = ws + O_WXT;
  float* WYT   = ws + O_WYT;
  float* ART   = ws + O_ART;
  float* MEAN  = ws + O_MEAN;
  float* ISTD  = ws + O_ISTD;
  f16*   X1PK  = (f16*)(ws + O_X1PK);
  int*   META  = (int*)(ws + O_META);
  int* HLOR = META;
  int* HCNTR= META + 64;
  int* WLOR = META + 128;
  int* HLOT = META + 448;
  int* HCNTT= META + 1472;
  int* WLOT = META + 2496;

  // ===== get_modulation branch =====
  k_pack_wc<<<2304, 256, 0, stream>>>(w_c1r, WC);
  k_padT<<<dim3(64, 32), 256, 0, stream>>>(feat1, FT2);
  k_conv_mfma<<<1408, 256, 0, stream>>>(WC, FT2, b_c1r, AH, PSC2);
  k_chan_fold8<<<8, 256, 0, stream>>>(PSC2, PSC2B);
  k_chan_final2<<<1, 256, 0, stream>>>(PSC2B, MEAN, ISTD);

  k_wxy<<<1, 64, 0, stream>>>(bb1, 64, 5, WXR, WYR, ARR, HLOR, HCNTR, WLOR);
  k_pool<5, false><<<dim3(64, 1), 256, 0, stream>>>(
      AH, WXR, WYR, ARR, HLOR, HCNTR, WLOR, MEAN, ISTD, g_c1r, be_c1r, nullptr, POOLR, 1);
  k_packx_h<<<dim3(25, 1), 256, 0, stream>>>(POOLR, PRPK, 64, 6400);

  k_packx_f<<<dim3(25, 8), 256, 0, stream>>>(w_f1r, WPK1R, 1024, 6400);
  k_gemm_f16pk<<<dim3(8, 1, 8), 256, 0, stream>>>(PRPK, WPK1R, PART, 6400, 1024, 25, 128);
  k_reduce_stats<<<dim3(4, 8), 256, 0, stream>>>(PART, b_f1r, Y1, 128, 64, 1024, 8, 8, PSUM, PSQ);
  k_fc_stats_final<<<4, 256, 0, stream>>>(PSUM, PSQ, 8, 1024, 64, MEAN, ISTD);
  k_fc_bn_relu_pk<<<512, 256, 0, stream>>>(Y1, MEAN, ISTD, g_f1r, be_f1r, X1PK, 128 * 1024, 1024, 64);

  k_packx_f<<<dim3(4, 2), 256, 0, stream>>>(w_f2r, WPK2R, 256, 1024);
  k_gemm_f16pk<<<dim3(2, 1, 4), 256, 0, stream>>>(X1PK, WPK2R, PART, 1024, 256, 8, 128);
  k_reduce_stats<<<dim3(1, 8), 256, 0, stream>>>(PART, b_f2r, MODp, 128, 64, 256, 4, 8, PSUM, PSQ);
  k_fc_stats_final<<<1, 256, 0, stream>>>(PSUM, PSQ, 8, 256, 64, MEAN, ISTD);
  k_fc_bn_relu<<<64, 256, 0, stream>>>(MODp, MEAN, ISTD, g_f2r, be_f2r, 64 * 256, 256);

  // ===== get_iou_feat branch =====
  k_pack_wc<<<2304, 256, 0, stream>>>(w_c1t, WC);
  k_padT<<<dim3(64, 32), 256, 0, stream>>>(feat2, FT2);
  k_conv_mfma<<<1408, 256, 0, stream>>>(WC, FT2, b_c1t, AH, PSC2);
  k_chan_fold8<<<8, 256, 0, stream>>>(PSC2, PSC2B);
  k_chan_final2<<<1, 256, 0, stream>>>(PSC2B, MEAN, ISTD);
  k_pad2<<<dim3(64, 36), 256, 0, stream>>>(AH, FT2, MEAN, ISTD, g_c1t, be_c1t);

  k_pack_wc<<<2304, 256, 0, stream>>>(w_c2t, WC);
  k_conv_mfma<<<1408, 256, 0, stream>>>(WC, FT2, b_c2t, AH, PSC2);
  k_chan_fold8<<<8, 256, 0, stream>>>(PSC2, PSC2B);
  k_chan_final2<<<1, 256, 0, stream>>>(PSC2B, MEAN, ISTD);

  // ===== predict_iou =====
  k_wxy<<<16, 64, 0, stream>>>(props, 1024, 7, WXT, WYT, ART, HLOT, HCNTT, WLOT);
  k_pool<7, true><<<dim3(64, 16), 256, 0, stream>>>(
      AH, WXT, WYT, ART, HLOT, HCNTT, WLOT, MEAN, ISTD, g_c2t, be_c2t, MODp, POOLT, 16);
  k_packx_h<<<dim3(49, 8), 256, 0, stream>>>(POOLT, PHPK, 1024, 12544);

  k_packx_f<<<dim3(49, 8), 256, 0, stream>>>(w_f1rt, WPK1RT, 1024, 12544);
  k_gemm_f16pk<<<dim3(8, 8, 8), 256, 0, stream>>>(PHPK, WPK1RT, PART, 12544, 1024, 49, 1024);
  k_reduce_stats<<<dim3(4, 128), 256, 0, stream>>>(PART, b_f1rt, Y1, 1024, 1024, 1024, 8, 8, PSUM, PSQ);
  k_fc_stats_final<<<4, 256, 0, stream>>>(PSUM, PSQ, 128, 1024, 1024, MEAN, ISTD);
  k_fc_bn_relu_pk<<<4096, 256, 0, stream>>>(Y1, MEAN, ISTD, g_f1rt, be_f1rt, X2PK, 1024 * 1024, 1024, 1024);

  k_packx_f<<<dim3(4, 8), 256, 0, stream>>>(w_f2rt, WPK2RT, 1024, 1024);
  k_gemm_f16pk<<<dim3(8, 8, 4), 256, 0, stream>>>(X2PK, WPK2RT, PART, 1024, 1024, 8, 1024);
  k_reduce_stats<<<dim3(4, 128), 256, 0, stream>>>(PART, b_f2rt, Y2, 1024, 1024, 1024, 4, 8, PSUM, PSQ);
  k_fc_stats_final<<<4, 256, 0, stream>>>(PSUM, PSQ, 128, 1024, 1024, MEAN, ISTD);
  k_fc_bn_relu<<<4096, 256, 0, stream>>>(Y2, MEAN, ISTD, g_f2rt, be_f2rt, 1024 * 1024, 1024);

  k_iou<<<1024, 256, 0, stream>>>(Y2, w_iou, b_iou, (float*)d_out);
}

// Round 19
// 838.442 us; speedup vs baseline: 1.0671x; 1.0545x over previous
//
#include <hip/hip_runtime.h>
#include <cstddef>

// ---------------------------------------------------------------------------
// FPNIoUNetHR forward — round 19: r18 config + vectorization basket
// (f16x8 pool stores, float4 padT reads, float4 iou dot). No structural
// changes. S=64, C=256, H=W=36, N=16.
// ---------------------------------------------------------------------------

typedef _Float16 f16;
typedef __attribute__((ext_vector_type(8))) _Float16 f16x8;
typedef __attribute__((ext_vector_type(4))) float f32x4;

__device__ __forceinline__ void gload16(const void* g, void* l) {
  __builtin_amdgcn_global_load_lds((const __attribute__((address_space(1))) void*)g,
                                   (__attribute__((address_space(3))) void*)l, 16, 0, 0);
}

// async global->VGPR load invisible to the compiler's waitcnt pass.
__device__ __forceinline__ f16x8 gload_reg(const f16* p) {
  f16x8 v;
  asm volatile("global_load_dwordx4 %0, %1, off" : "=&v"(v) : "v"(p) : "memory");
  return v;
}

#define WAITB(N) asm volatile("s_waitcnt vmcnt(" #N ")\n\ts_barrier" ::: "memory")
#define LGKB()   asm volatile("s_waitcnt lgkmcnt(0)\n\ts_barrier" ::: "memory")

static __device__ __forceinline__ float hat_int(float x) {
  float u = fminf(1.f, fmaxf(-1.f, x));
  float a = 0.5f * (1.f + u) * (1.f + u);
  float b = 0.5f + u - 0.5f * u * u;
  return (u <= 0.f) ? a : b;
}

// Packed GEMM operand layout: element (row,k) of a row-major [M][K] matrix ->
// [row/128][k/32][(k/8)%4][row%128][k%8]. One k-step chunk (128 rows x 32 k)
// is 8 KB contiguous, exactly the LDS image the MFMA frag reads want.
static __device__ __forceinline__ size_t pk_off(int row, int k, int K) {
  return (size_t)(row >> 7) * ((size_t)K * 128) + (size_t)(k >> 5) * 4096
       + (size_t)((((k >> 3) & 3) * 128 + (row & 127)) * 8 + (k & 7));
}

// ---- coalesced pad: fp32 CHW input -> FT2 f16, LDS transpose --------------
__global__ __launch_bounds__(256) void k_padT(const float* __restrict__ src,
                                              f16* __restrict__ FT) {
  __shared__ f16 sT[8][1300];
  const int img = blockIdx.x, kk = blockIdx.y;
  const float* sp = src + ((size_t)img * 256 + kk * 8) * 1296;
#pragma unroll
  for (int c = 0; c < 8; ++c) {
    const float4* sp4 = reinterpret_cast<const float4*>(sp + c * 1296);
    for (int i = threadIdx.x; i < 324; i += 256) {
      float4 v = sp4[i];
      f16* o = &sT[c][i * 4];
      o[0] = (f16)v.x; o[1] = (f16)v.y; o[2] = (f16)v.z; o[3] = (f16)v.w;
    }
  }
  __syncthreads();
  f16* op = FT + ((size_t)img * 32 + kk) * 1444 * 8;
  for (int i = threadIdx.x; i < 148; i += 256) {
    int r, cc;
    if (i < 38)       { r = 0;          cc = i; }
    else if (i < 76)  { r = 37;         cc = i - 38; }
    else if (i < 112) { r = i - 76 + 1; cc = 0; }
    else              { r = i - 112 + 1; cc = 37; }
    f16x8 z = {};
    *reinterpret_cast<f16x8*>(op + (r * 38 + cc) * 8) = z;
  }
  for (int i = threadIdx.x; i < 1296; i += 256) {
    const int h = i / 36, w = i - h * 36;
    f16x8 v;
#pragma unroll
    for (int c = 0; c < 8; ++c) v[c] = sT[c][i];
    *reinterpret_cast<f16x8*>(op + ((h + 1) * 38 + w + 1) * 8) = v;
  }
}

// ---- pad HWC f16 conv output + BN+ReLU -> FT2 f16 -------------------------
__global__ void k_pad2(const f16* __restrict__ yH, f16* __restrict__ FT,
                       const float* __restrict__ mean, const float* __restrict__ istd,
                       const float* __restrict__ g, const float* __restrict__ be) {
  const int img = blockIdx.x, h = blockIdx.y, c = threadIdx.x;
  const float sc = istd[c] * g[c];
  const float sh = be[c] - mean[c] * sc;
  const f16* sp = yH + ((size_t)img * 1296 + h * 36) * 256 + c;
  f16* op = FT + (((size_t)img * 32 + (c >> 3)) * 1444 + (h + 1) * 38 + 1) * 8 + (c & 7);
#pragma unroll 4
  for (int w = 0; w < 36; ++w) {
    float v = fmaxf(fmaf((float)sp[w * 256], sc, sh), 0.f);
    op[w * 8] = (f16)v;
  }
}

// ---- conv weights [256][256][3][3] fp32 -> packed f16 ---------------------
__global__ void k_pack_wc(const float* __restrict__ w, f16* __restrict__ dst) {
  int i = blockIdx.x * 256 + threadIdx.x;   // < 589,824
  int oct = i / 294912;
  int r = i - oct * 294912;
  int ks = r >> 12;
  int r2 = r & 4095;
  int koct = r2 >> 10;
  int r3 = r2 & 1023;
  int row = r3 >> 3, kj = r3 & 7;
  int k = ks * 32 + koct * 8 + kj;
  int t = k >> 8, c = k & 255;
  int oc = oct * 128 + row;
  dst[i] = (f16)w[(oc * 256 + c) * 9 + t];
}

// ---- tiled LDS transpose: row-major [M][K] -> pk layout (zero-fill) -------
__global__ __launch_bounds__(256) void k_packx_h(
    const f16* __restrict__ src, f16* __restrict__ dst, int M, int K) {
  __shared__ f16 sT[128][264];
  const int k0 = blockIdx.x * 256, r0 = blockIdx.y * 128;
  const int t = threadIdx.x;
  const int rl = t >> 5, kk = (t & 31) * 8;
  for (int rnd = 0; rnd < 16; ++rnd) {
    const int row_l = rl + rnd * 8;
    const int row = r0 + row_l;
    if (row < M) {
      f16x8 v = *reinterpret_cast<const f16x8*>(src + (size_t)row * K + k0 + kk);
      *reinterpret_cast<f16x8*>(&sT[row_l][kk]) = v;
    }
  }
  __syncthreads();
  const size_t base = (size_t)(r0 >> 7) * ((size_t)K * 128) + (size_t)(k0 >> 5) * 4096;
#pragma unroll
  for (int cs = 0; cs < 8; ++cs) {
#pragma unroll
    for (int half = 0; half < 2; ++half) {
      const int e = half * 256 + t;
      const int koct = e >> 7, row_l = e & 127;
      f16x8 v = {};
      if (r0 + row_l < M)
        v = *reinterpret_cast<const f16x8*>(&sT[row_l][cs * 32 + koct * 8]);
      *reinterpret_cast<f16x8*>(dst + base + (size_t)cs * 4096 + e * 8) = v;
    }
  }
}

__global__ __launch_bounds__(256) void k_packx_f(
    const float* __restrict__ src, f16* __restrict__ dst, int M, int K) {
  __shared__ f16 sT[128][264];
  const int k0 = blockIdx.x * 256, r0 = blockIdx.y * 128;
  const int t = threadIdx.x;
  const int rl = t >> 5, kk = (t & 31) * 8;
  for (int rnd = 0; rnd < 16; ++rnd) {
    const int row_l = rl + rnd * 8;
    const int row = r0 + row_l;
    if (row < M) {
      const float4* sp = reinterpret_cast<const float4*>(src + (size_t)row * K + k0 + kk);
      float4 a = sp[0], b = sp[1];
      f16* o = &sT[row_l][kk];
      o[0] = (f16)a.x; o[1] = (f16)a.y; o[2] = (f16)a.z; o[3] = (f16)a.w;
      o[4] = (f16)b.x; o[5] = (f16)b.y; o[6] = (f16)b.z; o[7] = (f16)b.w;
    }
  }
  __syncthreads();
  const size_t base = (size_t)(r0 >> 7) * ((size_t)K * 128) + (size_t)(k0 >> 5) * 4096;
#pragma unroll
  for (int cs = 0; cs < 8; ++cs) {
#pragma unroll
    for (int half = 0; half < 2; ++half) {
      const int e = half * 256 + t;
      const int koct = e >> 7, row_l = e & 127;
      f16x8 v = {};
      if (r0 + row_l < M)
        v = *reinterpret_cast<const f16x8*>(&sT[row_l][cs * 32 + koct * 8]);
      *reinterpret_cast<f16x8*>(dst + base + (size_t)cs * 4096 + e * 8) = v;
    }
  }
}

// ---- 3x3 conv: A in regs (asm), B via 4 LDS bufs, ONE barrier per step ----
// Restage targets the buffer consumed LAST step: before any wave passes the
// step-ks barrier it issued step-(ks-1) MFMAs, whose compiler lgkmcnt waits
// retired those ds_reads -> restage write cannot race a read.
__global__ __launch_bounds__(256, 2) void k_conv_mfma(
    const f16* __restrict__ Wpk, const f16* __restrict__ FT2,
    const float* __restrict__ bias, f16* __restrict__ yH,
    float* __restrict__ psc) {
  __shared__ __align__(16) char smem[36864];   // sB 4x8KB; epilogue 34.8KB
  f16x8* sB = (f16x8*)smem;            // 4 buffers x 512
  const int bid = blockIdx.x;
  const int orig = (bid & 7) * 176 + (bid >> 3);   // bijective: 1408 % 8 == 0
  const int img = orig / 22;
  const int rem = orig - img * 22;
  const int oct = rem / 11;
  const int pt  = rem - oct * 11;
  const int m0 = oct * 128;
  const int p0 = pt * 128;
  const int tid = threadIdx.x;
  const int lane = tid & 63;
  const int wv = tid >> 6;
  const int wr = wv >> 1, wc = wv & 1;

  const f16* aFrag = Wpk + (size_t)oct * 294912 + ((lane >> 4) << 10)
                   + ((size_t)(wr * 64 + (lane & 15)) << 3);
  const f16* ftImg = FT2 + (size_t)img * 32 * 1444 * 8;
  int pos0 = p0 + lane;
  int pc0 = min(pos0, 1295);
  int pc1 = min(pos0 + 64, 1295);
  int pb0 = (pc0 / 36) * 38 + (pc0 % 36);
  int pb1 = (pc1 / 36) * 38 + (pc1 % 36);

  const int loff = wv * 2048 + lane * 16;

  auto stageB = [&](int buf, int ks) {
    const int t = ks >> 3;
    const int dy = t / 3, dx = t - dy * 3;
    const int cs = ks & 7;
    const int dyx = dy * 38 + dx;
    char* lB = (char*)sB + buf * 8192 + loff;
    const f16* bp = ftImg + ((size_t)(cs * 4 + wv) * 1444 + dyx) * 8;
    gload16(bp + pb0 * 8, lB);
    gload16(bp + pb1 * 8, lB + 1024);
  };

#define LOADA(ASET, KS)                                                        \
  {                                                                            \
    const f16* _p = aFrag + (size_t)(KS) * 4096;                               \
    ASET[0] = gload_reg(_p);                                                   \
    ASET[1] = gload_reg(_p + 128);                                             \
    ASET[2] = gload_reg(_p + 256);                                             \
    ASET[3] = gload_reg(_p + 384);                                             \
  }

  f32x4 acc[4][4] = {};
  const int fidxB = ((lane >> 4) << 7) + wc * 64 + (lane & 15);
  f16x8 A0[4], A1[4], A2[4];

  stageB(0, 0); LOADA(A0, 0);
  stageB(1, 1); LOADA(A1, 1);
  stageB(2, 2); LOADA(A2, 2);   // 18 VMEM ops in flight per wave

#define CSTEP(ASET, BUF, RBUF, KS)                                             \
  {                                                                            \
    const int rr = 71 - (KS);                                                  \
    if (rr >= 2)      WAITB(12);                                               \
    else if (rr == 1) WAITB(6);                                                \
    else              WAITB(0);                                                \
    __builtin_amdgcn_sched_barrier(0);                                         \
    f16x8 bf[4];                                                               \
    _Pragma("unroll") for (int j = 0; j < 4; ++j)                              \
      bf[j] = sB[(BUF) * 512 + fidxB + j * 16];                                \
    __builtin_amdgcn_s_setprio(1);                                             \
    _Pragma("unroll") for (int ii = 0; ii < 4; ++ii)                           \
      _Pragma("unroll") for (int jj = 0; jj < 4; ++jj)                         \
        acc[ii][jj] = __builtin_amdgcn_mfma_f32_16x16x32_f16(ASET[ii], bf[jj], acc[ii][jj], 0, 0, 0); \
    __builtin_amdgcn_s_setprio(0);                                             \
    if ((KS) + 3 < 72) { stageB(RBUF, (KS) + 3); LOADA(ASET, (KS) + 3); }      \
  }

  for (int ks = 0; ks < 72; ks += 12) {
    CSTEP(A0, 0, 3, ks);
    CSTEP(A1, 1, 0, ks + 1);
    CSTEP(A2, 2, 1, ks + 2);
    CSTEP(A0, 3, 2, ks + 3);
    CSTEP(A1, 0, 3, ks + 4);
    CSTEP(A2, 1, 0, ks + 5);
    CSTEP(A0, 2, 1, ks + 6);
    CSTEP(A1, 3, 2, ks + 7);
    CSTEP(A2, 0, 3, ks + 8);
    CSTEP(A0, 1, 0, ks + 9);
    CSTEP(A1, 2, 1, ks + 10);
    CSTEP(A2, 3, 2, ks + 11);
  }
#undef CSTEP
#undef LOADA

  // ---- epilogue: acc -> LDS [128 pos][128 oc] (+pad) -> coalesced stores --
  __syncthreads();
  f16* sE = (f16*)smem;                 // 128 x 136 f16 = 34.8 KB
  const int ocl = wr * 64 + ((lane >> 4) << 2);
#pragma unroll
  for (int i = 0; i < 4; ++i) {
    const int oc0 = m0 + ocl + i * 16;
    float b0 = bias[oc0], b1 = bias[oc0 + 1], b2 = bias[oc0 + 2], b3 = bias[oc0 + 3];
#pragma unroll
    for (int j = 0; j < 4; ++j) {
      f16* e = &sE[(wc * 64 + j * 16 + (lane & 15)) * 136 + ocl + i * 16];
      e[0] = (f16)(acc[i][j][0] + b0);
      e[1] = (f16)(acc[i][j][1] + b1);
      e[2] = (f16)(acc[i][j][2] + b2);
      e[3] = (f16)(acc[i][j][3] + b3);
    }
  }
  __syncthreads();
  f16* yb = yH + (size_t)img * 1296 * 256 + m0;
#pragma unroll
  for (int it = 0; it < 8; ++it) {
    const int e = (it * 256 + tid) * 8;
    const int row = e >> 7;
    const int oc = e & 127;
    const int col = p0 + row;
    if (col < 1296)
      *reinterpret_cast<f16x8*>(yb + (size_t)col * 256 + oc) =
        *reinterpret_cast<const f16x8*>(&sE[row * 136 + oc]);
  }
  // ---- channel stats partials: 256 threads = 2 row-halves x 128 oc --------
  const int nvalid = min(128, 1296 - p0);
  const int half = tid >> 7, cc = tid & 127;
  const int r0 = half * 64, r1 = min(nvalid, r0 + 64);
  float s = 0.f, ss = 0.f;
  for (int row = r0; row < r1; ++row) {
    float v = (float)sE[row * 136 + cc];
    s += v; ss += v * v;
  }
  const int bi = (half * 704 + img * 11 + pt) * 256 + m0 + cc;
  psc[bi] = s;
  psc[360448 + bi] = ss;
}

// ---- fold conv stats partials: 1408 entries -> 8 -> mean/istd -------------
__global__ void k_chan_fold8(const float* __restrict__ psc, float* __restrict__ out2) {
  const int z = blockIdx.x, c = threadIdx.x;
  float s = 0.f, ss = 0.f;
  for (int i = z * 176; i < z * 176 + 176; ++i) {
    s += psc[i * 256 + c];
    ss += psc[360448 + i * 256 + c];
  }
  out2[z * 256 + c] = s;
  out2[2048 + z * 256 + c] = ss;
}

__global__ void k_chan_final2(const float* __restrict__ out2,
                              float* __restrict__ mean, float* __restrict__ istd) {
  const int c = threadIdx.x;
  float s = 0.f, ss = 0.f;
#pragma unroll
  for (int z = 0; z < 8; ++z) { s += out2[z * 256 + c]; ss += out2[2048 + z * 256 + c]; }
  float m = s * (1.f / 82944.f);
  float var = ss * (1.f / 82944.f) - m * m;
  mean[c] = m;
  istd[c] = rsqrtf(var + 1e-5f);
}

// ---- packed split-K f16 MFMA GEMM, 3-deep counted-vmcnt pipeline ----------
__global__ __launch_bounds__(256) void k_gemm_f16pk(
    const f16* __restrict__ Apk, const f16* __restrict__ Bpk,
    float* __restrict__ part, int K, int Nout, int stepsPerZ, int mrows) {
  __shared__ f16x8 sA[1536];
  __shared__ f16x8 sB[1536];
  const int nt = blockIdx.x, mt = blockIdx.y, z = blockIdx.z;
  const int tid = threadIdx.x;
  const int lane = tid & 63;
  const int wv = tid >> 6;
  const int wr = wv >> 1, wc = wv & 1;

  const f16* aC = Apk + (size_t)mt * K * 128 + wv * 1024 + lane * 8;
  const f16* bC = Bpk + (size_t)nt * K * 128 + wv * 1024 + lane * 8;
  const int loff = wv * 2048 + lane * 16;

  auto stage = [&](int buf, int ks) {
    char* lA = (char*)sA + buf * 8192 + loff;
    char* lB = (char*)sB + buf * 8192 + loff;
    const f16* ap = aC + (size_t)ks * 4096;
    const f16* bp = bC + (size_t)ks * 4096;
    gload16(ap, lA);
    gload16(ap + 512, lA + 1024);
    gload16(bp, lB);
    gload16(bp + 512, lB + 1024);
  };

  f32x4 acc[4][4] = {};
  const int fidxA = ((lane >> 4) << 7) + wr * 64 + (lane & 15);
  const int fidxB = ((lane >> 4) << 7) + wc * 64 + (lane & 15);

  const int ks0 = z * stepsPerZ;
  stage(0, ks0); stage(1, ks0 + 1); stage(2, ks0 + 2);
  int cur = 0;
  for (int i = 0; i < stepsPerZ; ++i) {
    const int r = stepsPerZ - 1 - i;
    if (r >= 2)      WAITB(8);
    else if (r == 1) WAITB(4);
    else             WAITB(0);
    const int base = cur * 512;
    f16x8 af[4], bf[4];
#pragma unroll
    for (int j = 0; j < 4; ++j) {
      af[j] = sA[base + fidxA + j * 16];
      bf[j] = sB[base + fidxB + j * 16];
    }
    __builtin_amdgcn_s_setprio(1);
#pragma unroll
    for (int ii = 0; ii < 4; ++ii)
#pragma unroll
      for (int jj = 0; jj < 4; ++jj)
        acc[ii][jj] = __builtin_amdgcn_mfma_f32_16x16x32_f16(af[ii], bf[jj], acc[ii][jj], 0, 0, 0);
    __builtin_amdgcn_s_setprio(0);
    LGKB();
    if (i + 3 < stepsPerZ) stage(cur, ks0 + i + 3);
    cur = (cur == 2) ? 0 : cur + 1;
  }

  const size_t zoff = (size_t)z * mrows * Nout;
  const int colb = nt * 128 + wc * 64 + (lane & 15);
  const int rowb = mt * 128 + wr * 64 + ((lane >> 4) << 2);
#pragma unroll
  for (int i = 0; i < 4; ++i)
#pragma unroll
    for (int j = 0; j < 4; ++j)
#pragma unroll
      for (int r = 0; r < 4; ++r)
        part[zoff + (size_t)(rowb + i * 16 + r) * Nout + colb + j * 16] = acc[i][j][r];
}

// ---- fused: reduce split-K partials + bias + FC BN partial stats ----------
__global__ void k_reduce_stats(const float* __restrict__ part, const float* __restrict__ bias,
                               float* __restrict__ out, int mrows, int Mout, int Nout,
                               int sk, int rpz,
                               float* __restrict__ psum, float* __restrict__ psq) {
  const int col = blockIdx.x * 256 + threadIdx.x;
  const int z = blockIdx.y;
  const float b = bias[col];
  float s = 0.f, ss = 0.f;
  const int r0 = z * rpz, r1 = min(Mout, r0 + rpz);
  for (int m = r0; m < r1; ++m) {
    float v = b;
    for (int zz = 0; zz < sk; ++zz)
      v += part[(size_t)zz * mrows * Nout + (size_t)m * Nout + col];
    out[(size_t)m * Nout + col] = v;
    s += v; ss += v * v;
  }
  psum[(size_t)z * Nout + col] = s;
  psq[(size_t)z * Nout + col] = ss;
}

// ---- PrRoI separable weights + sparse-range metadata ----------------------
__global__ void k_wxy(const float* __restrict__ rois, int ntot, int P,
                      float* __restrict__ Wx, float* __restrict__ Wy,
                      float* __restrict__ area,
                      int* __restrict__ HLO, int* __restrict__ HCNT,
                      int* __restrict__ WLO) {
  int idx = blockIdx.x * blockDim.x + threadIdx.x;
  if (idx >= ntot) return;
  float rx = rois[idx * 4 + 0], ry = rois[idx * 4 + 1];
  float rw = rois[idx * 4 + 2], rh = rois[idx * 4 + 3];
  float x1 = rx * 0.125f, y1 = ry * 0.125f;
  float x2 = (rx + rw) * 0.125f, y2 = (ry + rh) * 0.125f;
  float bw = (x2 - x1) / P, bh = (y2 - y1) / P;
  area[idx] = bw * bh;
  int hlo = max(0, (int)ceilf(y1 - 1.f));
  int hhi = min(35, (int)floorf(y2 + 1.f));
  HLO[idx] = hlo;
  HCNT[idx] = max(0, hhi - hlo + 1);
  for (int q = 0; q < P; ++q) {
    float xlo = x1 + q * bw, ylo = y1 + q * bh;
    WLO[idx * P + q] = min(31, max(0, (int)ceilf(xlo - 1.f)));
    for (int g = 0; g < 36; ++g) {
      float fg = (float)g;
      Wx[(idx * P + q) * 36 + g] = hat_int(xlo + bw - fg) - hat_int(xlo - fg);
      Wy[(idx * P + q) * 36 + g] = hat_int(ylo + bh - fg) - hat_int(ylo - fg);
    }
  }
}

// ---- PrRoI pool from HWC f16 with fused BN+ReLU, DENSE row-major output ---
template <int P, bool MOD>
__global__ __launch_bounds__(256) void k_pool(
    const f16* __restrict__ feat, const float* __restrict__ Wx,
    const float* __restrict__ Wy, const float* __restrict__ area,
    const int* __restrict__ HLO, const int* __restrict__ HCNT,
    const int* __restrict__ WLO,
    const float* __restrict__ mean, const float* __restrict__ istd,
    const float* __restrict__ g, const float* __restrict__ be,
    const float* __restrict__ mod, f16* __restrict__ out, int N) {
  const int s = blockIdx.x, n = blockIdx.y;
  const int idx = s * N + n;
  const int c = threadIdx.x;
  constexpr int KD = P * P * 256;
  __shared__ __align__(16) f16 sOut[KD];
  __shared__ float sWx[P * 36], sWy[P * 36];
  __shared__ int sWLO[P];
  __shared__ int sH[2];
  for (int i = threadIdx.x; i < P * 36; i += 256) {
    sWx[i] = Wx[(size_t)idx * P * 36 + i];
    sWy[i] = Wy[(size_t)idx * P * 36 + i];
  }
  if (threadIdx.x < P) sWLO[threadIdx.x] = WLO[idx * P + threadIdx.x];
  if (threadIdx.x == 0) { sH[0] = HLO[idx]; sH[1] = HCNT[idx]; }
  __syncthreads();
  const float sc = istd[c] * g[c];
  const float sh = be[c] - mean[c] * sc;
  const f16* f = feat + (size_t)s * 1296 * 256 + c;
  float o[P][P] = {};
  const int hlo = sH[0], hcnt = sH[1];
  for (int hh = 0; hh < hcnt; ++hh) {
    const int h = hlo + hh;
    const f16* rp = f + (size_t)h * 36 * 256;
    float colsum[P];
#pragma unroll
    for (int q = 0; q < P; ++q) {
      const int w0 = sWLO[q];
      const f16* wp = rp + (size_t)w0 * 256;
      float v = 0.f;
#pragma unroll
      for (int j = 0; j < 5; ++j) {
        float x = fmaxf(fmaf((float)wp[j * 256], sc, sh), 0.f);
        v = fmaf(sWx[q * 36 + w0 + j], x, v);
      }
      colsum[q] = v;
    }
#pragma unroll
    for (int p = 0; p < P; ++p) {
      const float wy = sWy[p * 36 + h];
      if (wy != 0.f) {
#pragma unroll
        for (int q = 0; q < P; ++q) o[p][q] = fmaf(wy, colsum[q], o[p][q]);
      }
    }
  }
  float a = area[idx];
  float inv = (a > 0.f) ? 1.f / fmaxf(a, 1e-12f) : 0.f;
  float msc = MOD ? (mod[s * 256 + c] * inv) : inv;
  const int kbase = c * (P * P);
#pragma unroll
  for (int p = 0; p < P; ++p)
#pragma unroll
    for (int q = 0; q < P; ++q)
      sOut[kbase + p * P + q] = (f16)(o[p][q] * msc);
  __syncthreads();
  const f16x8* so8 = reinterpret_cast<const f16x8*>(sOut);
  f16x8* op8 = reinterpret_cast<f16x8*>(out + (size_t)idx * KD);
  for (int j = threadIdx.x; j < KD / 8; j += 256) op8[j] = so8[j];
}

// ---- FC BN stats pass 2 ---------------------------------------------------
__global__ void k_fc_stats_final(const float* __restrict__ psum, const float* __restrict__ psq,
                                 int nz, int Nf, int M,
                                 float* __restrict__ mean, float* __restrict__ istd) {
  int col = blockIdx.x * 256 + threadIdx.x;
  if (col >= Nf) return;
  float s = 0.f, ss = 0.f;
  for (int z = 0; z < nz; ++z) {
    s += psum[(size_t)z * Nf + col];
    ss += psq[(size_t)z * Nf + col];
  }
  float mu = s / (float)M;
  float var = ss / (float)M - mu * mu;
  mean[col] = mu;
  istd[col] = rsqrtf(var + 1e-5f);
}

// ---- FC BN+ReLU elementwise (fp32 in place) -------------------------------
__global__ void k_fc_bn_relu(float* __restrict__ y, const float* __restrict__ mean,
                             const float* __restrict__ istd, const float* __restrict__ g,
                             const float* __restrict__ be, int total, int Nf) {
  int i = blockIdx.x * 256 + threadIdx.x;
  if (i >= total) return;
  int col = i % Nf;
  float sc = istd[col] * g[col];
  float sh = be[col] - mean[col] * sc;
  y[i] = fmaxf(fmaf(y[i], sc, sh), 0.f);
}

// ---- FC BN+ReLU -> packed f16; rows >= Mvalid write 0 (pad rows) ----------
__global__ void k_fc_bn_relu_pk(const float* __restrict__ y, const float* __restrict__ mean,
                                const float* __restrict__ istd, const float* __restrict__ g,
                                const float* __restrict__ be, f16* __restrict__ xpk,
                                int total, int Nf, int Mvalid) {
  int i = blockIdx.x * 256 + threadIdx.x;
  if (i >= total) return;
  int row = i / Nf, col = i - row * Nf;
  float v = 0.f;
  if (row < Mvalid) {
    float sc = istd[col] * g[col];
    float sh = be[col] - mean[col] * sc;
    v = fmaxf(fmaf(y[i], sc, sh), 0.f);
  }
  xpk[pk_off(row, col, Nf)] = (f16)v;
}

// ---- IoU head (float4 dot) -------------------------------------------------
__global__ void k_iou(const float* __restrict__ x, const float* __restrict__ w,
                      const float* __restrict__ b, float* __restrict__ out) {
  const int r = blockIdx.x, tid = threadIdx.x;
  float4 xv = reinterpret_cast<const float4*>(x + (size_t)r * 1024)[tid];
  float4 wv = reinterpret_cast<const float4*>(w)[tid];
  float s = xv.x * wv.x + xv.y * wv.y + xv.z * wv.z + xv.w * wv.w;
  __shared__ float red[256];
  red[tid] = s;
  __syncthreads();
  for (int o = 128; o > 0; o >>= 1) {
    if (tid < o) red[tid] += red[tid + o];
    __syncthreads();
  }
  if (tid == 0) out[r] = red[0] + b[0];
}

// ---------------------------------------------------------------------------
// Workspace layout (float offsets). Same as round 18.
// ---------------------------------------------------------------------------
static const size_t O_A      = 0;
static const size_t O_POOLT  = 12000000;
static const size_t O_PSC2   = 12000000;
static const size_t O_PSC2B  = 12800000;
static const size_t O_PSUM   = 13000000;
static const size_t O_PSQ    = 13200000;
static const size_t O_WPK2RT = 16000000;
static const size_t O_POOLR  = 18500000;
static const size_t O_WPK2R  = 20000000;
static const size_t O_FT     = 21233664;
static const size_t O_X2PK   = 21233664 + 6422528;
static const size_t O_WC     = 33062912;
static const size_t O_WPK1RT = 33357824;
static const size_t O_WPK1R  = 39780352;
static const size_t O_PRPK   = 43057152;
static const size_t O_Y1     = 43466752;
static const size_t O_Y2     = 44515328;
static const size_t O_MOD    = 45563904;
static const size_t O_WXR    = 45580288;
static const size_t O_WYR    = 45591808;
static const size_t O_ARR    = 45603328;
static const size_t O_WXT    = 45603392;
static const size_t O_WYT    = 45861440;
static const size_t O_ART    = 46119488;
static const size_t O_MEAN   = 46120512;
static const size_t O_ISTD   = 46121536;
static const size_t O_X1PK   = 46122560;
static const size_t O_META   = 46188096;

extern "C" void kernel_launch(void* const* d_in, const int* in_sizes, int n_in,
                              void* d_out, int out_size, void* d_ws, size_t ws_size,
                              hipStream_t stream) {
  (void)in_sizes; (void)n_in; (void)out_size; (void)ws_size;
  const float* feat1  = (const float*)d_in[0];
  const float* feat2  = (const float*)d_in[1];
  const float* bb1    = (const float*)d_in[2];
  const float* props  = (const float*)d_in[3];
  const float* w_c1r  = (const float*)d_in[4];
  const float* b_c1r  = (const float*)d_in[5];
  const float* g_c1r  = (const float*)d_in[6];
  const float* be_c1r = (const float*)d_in[7];
  const float* w_c1t  = (const float*)d_in[8];
  const float* b_c1t  = (const float*)d_in[9];
  const float* g_c1t  = (const float*)d_in[10];
  const float* be_c1t = (const float*)d_in[11];
  const float* w_c2t  = (const float*)d_in[12];
  const float* b_c2t  = (const float*)d_in[13];
  const float* g_c2t  = (const float*)d_in[14];
  const float* be_c2t = (const float*)d_in[15];
  const float* w_f1r  = (const float*)d_in[16];
  const float* b_f1r  = (const float*)d_in[17];
  const float* g_f1r  = (const float*)d_in[18];
  const float* be_f1r = (const float*)d_in[19];
  const float* w_f2r  = (const float*)d_in[20];
  const float* b_f2r  = (const float*)d_in[21];
  const float* g_f2r  = (const float*)d_in[22];
  const float* be_f2r = (const float*)d_in[23];
  const float* w_f1rt = (const float*)d_in[24];
  const float* b_f1rt = (const float*)d_in[25];
  const float* g_f1rt = (const float*)d_in[26];
  const float* be_f1rt= (const float*)d_in[27];
  const float* w_f2rt = (const float*)d_in[28];
  const float* b_f2rt = (const float*)d_in[29];
  const float* g_f2rt = (const float*)d_in[30];
  const float* be_f2rt= (const float*)d_in[31];
  const float* w_iou  = (const float*)d_in[32];
  const float* b_iou  = (const float*)d_in[33];

  float* ws    = (float*)d_ws;
  f16*   AH    = (f16*)(ws + O_A);
  float* PART  = ws + O_A;
  f16*   POOLT = (f16*)(ws + O_POOLT);
  float* PSC2  = ws + O_PSC2;
  float* PSC2B = ws + O_PSC2B;
  float* PSUM  = ws + O_PSUM;
  float* PSQ   = ws + O_PSQ;
  f16*   WPK2RT= (f16*)(ws + O_WPK2RT);
  f16*   POOLR = (f16*)(ws + O_POOLR);
  f16*   WPK2R = (f16*)(ws + O_WPK2R);
  f16*   FT2   = (f16*)(ws + O_FT);
  f16*   PHPK  = FT2;
  f16*   X2PK  = (f16*)(ws + O_X2PK);
  f16*   WC    = (f16*)(ws + O_WC);
  f16*   WPK1RT= (f16*)(ws + O_WPK1RT);
  f16*   WPK1R = (f16*)(ws + O_WPK1R);
  f16*   PRPK  = (f16*)(ws + O_PRPK);
  float* Y1    = ws + O_Y1;
  float* Y2    = ws + O_Y2;
  float* MODp  = ws + O_MOD;
  float* WXR   = ws + O_WXR;
  float* WYR   = ws + O_WYR;
  float* ARR   = ws + O_ARR;
  float* WXT   = ws + O_WXT;
  float* WYT   = ws + O_WYT;
  float* ART   = ws + O_ART;
  float* MEAN  = ws + O_MEAN;
  float* ISTD  = ws + O_ISTD;
  f16*   X1PK  = (f16*)(ws + O_X1PK);
  int*   META  = (int*)(ws + O_META);
  int* HLOR = META;
  int* HCNTR= META + 64;
  int* WLOR = META + 128;
  int* HLOT = META + 448;
  int* HCNTT= META + 1472;
  int* WLOT = META + 2496;

  // ===== get_modulation branch =====
  k_pack_wc<<<2304, 256, 0, stream>>>(w_c1r, WC);
  k_padT<<<dim3(64, 32), 256, 0, stream>>>(feat1, FT2);
  k_conv_mfma<<<1408, 256, 0, stream>>>(WC, FT2, b_c1r, AH, PSC2);
  k_chan_fold8<<<8, 256, 0, stream>>>(PSC2, PSC2B);
  k_chan_final2<<<1, 256, 0, stream>>>(PSC2B, MEAN, ISTD);

  k_wxy<<<1, 64, 0, stream>>>(bb1, 64, 5, WXR, WYR, ARR, HLOR, HCNTR, WLOR);
  k_pool<5, false><<<dim3(64, 1), 256, 0, stream>>>(
      AH, WXR, WYR, ARR, HLOR, HCNTR, WLOR, MEAN, ISTD, g_c1r, be_c1r, nullptr, POOLR, 1);
  k_packx_h<<<dim3(25, 1), 256, 0, stream>>>(POOLR, PRPK, 64, 6400);

  k_packx_f<<<dim3(25, 8), 256, 0, stream>>>(w_f1r, WPK1R, 1024, 6400);
  k_gemm_f16pk<<<dim3(8, 1, 8), 256, 0, stream>>>(PRPK, WPK1R, PART, 6400, 1024, 25, 128);
  k_reduce_stats<<<dim3(4, 8), 256, 0, stream>>>(PART, b_f1r, Y1, 128, 64, 1024, 8, 8, PSUM, PSQ);
  k_fc_stats_final<<<4, 256, 0, stream>>>(PSUM, PSQ, 8, 1024, 64, MEAN, ISTD);
  k_fc_bn_relu_pk<<<512, 256, 0, stream>>>(Y1, MEAN, ISTD, g_f1r, be_f1r, X1PK, 128 * 1024, 1024, 64);

  k_packx_f<<<dim3(4, 2), 256, 0, stream>>>(w_f2r, WPK2R, 256, 1024);
  k_gemm_f16pk<<<dim3(2, 1, 4), 256, 0, stream>>>(X1PK, WPK2R, PART, 1024, 256, 8, 128);
  k_reduce_stats<<<dim3(1, 8), 256, 0, stream>>>(PART, b_f2r, MODp, 128, 64, 256, 4, 8, PSUM, PSQ);
  k_fc_stats_final<<<1, 256, 0, stream>>>(PSUM, PSQ, 8, 256, 64, MEAN, ISTD);
  k_fc_bn_relu<<<64, 256, 0, stream>>>(MODp, MEAN, ISTD, g_f2r, be_f2r, 64 * 256, 256);

  // ===== get_iou_feat branch =====
  k_pack_wc<<<2304, 256, 0, stream>>>(w_c1t, WC);
  k_padT<<<dim3(64, 32), 256, 0, stream>>>(feat2, FT2);
  k_conv_mfma<<<1408, 256, 0, stream>>>(WC, FT2, b_c1t, AH, PSC2);
  k_chan_fold8<<<8, 256, 0, stream>>>(PSC2, PSC2B);
  k_chan_final2<<<1, 256, 0, stream>>>(PSC2B, MEAN, ISTD);
  k_pad2<<<dim3(64, 36), 256, 0, stream>>>(AH, FT2, MEAN, ISTD, g_c1t, be_c1t);

  k_pack_wc<<<2304, 256, 0, stream>>>(w_c2t, WC);
  k_conv_mfma<<<1408, 256, 0, stream>>>(WC, FT2, b_c2t, AH, PSC2);
  k_chan_fold8<<<8, 256, 0, stream>>>(PSC2, PSC2B);
  k_chan_final2<<<1, 256, 0, stream>>>(PSC2B, MEAN, ISTD);

  // ===== predict_iou =====
  k_wxy<<<16, 64, 0, stream>>>(props, 1024, 7, WXT, WYT, ART, HLOT, HCNTT, WLOT);
  k_pool<7, true><<<dim3(64, 16), 256, 0, stream>>>(
      AH, WXT, WYT, ART, HLOT, HCNTT, WLOT, MEAN, ISTD, g_c2t, be_c2t, MODp, POOLT, 16);
  k_packx_h<<<dim3(49, 8), 256, 0, stream>>>(POOLT, PHPK, 1024, 12544);

  k_packx_f<<<dim3(49, 8), 256, 0, stream>>>(w_f1rt, WPK1RT, 1024, 12544);
  k_gemm_f16pk<<<dim3(8, 8, 8), 256, 0, stream>>>(PHPK, WPK1RT, PART, 12544, 1024, 49, 1024);
  k_reduce_stats<<<dim3(4, 128), 256, 0, stream>>>(PART, b_f1rt, Y1, 1024, 1024, 1024, 8, 8, PSUM, PSQ);
  k_fc_stats_final<<<4, 256, 0, stream>>>(PSUM, PSQ, 128, 1024, 1024, MEAN, ISTD);
  k_fc_bn_relu_pk<<<4096, 256, 0, stream>>>(Y1, MEAN, ISTD, g_f1rt, be_f1rt, X2PK, 1024 * 1024, 1024, 1024);

  k_packx_f<<<dim3(4, 8), 256, 0, stream>>>(w_f2rt, WPK2RT, 1024, 1024);
  k_gemm_f16pk<<<dim3(8, 8, 4), 256, 0, stream>>>(X2PK, WPK2RT, PART, 1024, 1024, 8, 1024);
  k_reduce_stats<<<dim3(4, 128), 256, 0, stream>>>(PART, b_f2rt, Y2, 1024, 1024, 1024, 4, 8, PSUM, PSQ);
  k_fc_stats_final<<<4, 256, 0, stream>>>(PSUM, PSQ, 128, 1024, 1024, MEAN, ISTD);
  k_fc_bn_relu<<<4096, 256, 0, stream>>>(Y2, MEAN, ISTD, g_f2rt, be_f2rt, 1024 * 1024, 1024);

  k_iou<<<1024, 256, 0, stream>>>(Y2, w_iou, b_iou, (float*)d_out);
}